// Round 1
// baseline (6877.962 us; speedup 1.0000x reference)
//
#include <hip/hip_runtime.h>

// Problem constants
#define D_DIM 256
#define V_DIM 8192
#define B_DIM 64
#define T_DIM 16
#define L_DIM 1024          // B*T
#define NROW 65536          // L*64 rows of f_rest / z_LND
#define NELEM 16777216      // NROW * D

// Output layout (all float32 in d_out)
#define OUT_LOSS 16777216
#define OUT_IDX  16777217
#define OUT_CS   16864257

// Workspace float offsets (all 16B aligned)
#define EN_OFF    ((size_t)0)
#define ESUM_OFF  ((size_t)2097152)
#define E0_OFF    ((size_t)4194304)
#define E2_OFF    ((size_t)6291456)
#define WSUM_OFF  ((size_t)8388608)
#define W0_OFF    ((size_t)8454144)
#define W2_OFF    ((size_t)8519680)
#define ZLND_OFF  ((size_t)8585216)
#define FREST_OFF ((size_t)25362432)
#define Q_OFF     ((size_t)42139648)
#define PM1_OFF   ((size_t)58916864)
#define PI1_OFF   ((size_t)59179008)
#define PM2_OFF   ((size_t)59441152)
#define PI2_OFF   ((size_t)59703296)
#define IDXI_OFF  ((size_t)59965440)
#define CNT_OFF   ((size_t)60052480)
#define LOSS_OFF  ((size_t)60060672)

__device__ __forceinline__ float blk_reduce_sum(float v, float* sb) {
#pragma unroll
    for (int off = 32; off; off >>= 1) v += __shfl_down(v, off, 64);
    const int w = threadIdx.x >> 6;
    if ((threadIdx.x & 63) == 0) sb[w] = v;
    __syncthreads();
    return sb[0] + sb[1] + sb[2] + sb[3];
}

// Normalize embedding rows: e_n = emb / max(||emb||, 1e-12)
__global__ void k_norm_embed(const float* __restrict__ emb, float* __restrict__ en) {
    __shared__ float sb[4];
    const int v = blockIdx.x, o = threadIdx.x;
    const float x = emb[(size_t)v * D_DIM + o];
    const float ss = blk_reduce_sum(x * x, sb);
    const float sc = 1.0f / fmaxf(sqrtf(ss), 1e-12f);
    en[(size_t)v * D_DIM + o] = x * sc;
}

// Transpose-repack phi_w (D,D,3) into Wsum / W0 / W2, each (o,i) row-major
__global__ void k_prep_w(const float* __restrict__ pw, float* __restrict__ wsum,
                         float* __restrict__ w0, float* __restrict__ w2) {
    const int i = blockIdx.x * 256 + threadIdx.x;  // 0..65535
    const float a = pw[(size_t)i * 3 + 0];
    const float b = pw[(size_t)i * 3 + 1];
    const float c = pw[(size_t)i * 3 + 2];
    wsum[i] = a + b + c; w0[i] = a; w2[i] = c;
}

// E_k = e_n @ Wk^T  (V x 256) = (V x 256)(256 x 256); grid (V/128, 2, 3)
__global__ __launch_bounds__(256) void k_phi_gemm(
    const float* __restrict__ en, const float* __restrict__ wsum,
    const float* __restrict__ w0, const float* __restrict__ w2,
    float* __restrict__ esum, float* __restrict__ e0, float* __restrict__ e2) {
    __shared__ __align__(16) float smem[4096];
    float (*As)[128] = (float (*)[128])smem;
    float (*Bs)[128] = (float (*)[128])(smem + 2048);
    const float* Bm; float* Cm;
    if (blockIdx.z == 0)      { Bm = wsum; Cm = esum; }
    else if (blockIdx.z == 1) { Bm = w0;   Cm = e0;   }
    else                      { Bm = w2;   Cm = e2;   }
    const int tid = threadIdx.x, tx = tid & 15, ty = tid >> 4;
    const int rowbase = blockIdx.x * 128, colbase = blockIdx.y * 128;
    float acc[8][8];
#pragma unroll
    for (int r = 0; r < 8; r++)
#pragma unroll
        for (int c = 0; c < 8; c++) acc[r][c] = 0.f;
    for (int kb = 0; kb < 256; kb += 16) {
        __syncthreads();
        {
            const int lr = tid >> 1, k0 = (tid & 1) << 3;
            const float4* ap = (const float4*)(en + ((size_t)(rowbase + lr)) * 256 + kb + k0);
            const float4 a0 = ap[0], a1 = ap[1];
            const float4* bp = (const float4*)(Bm + ((size_t)(colbase + lr)) * 256 + kb + k0);
            const float4 b0 = bp[0], b1 = bp[1];
            As[k0+0][lr]=a0.x; As[k0+1][lr]=a0.y; As[k0+2][lr]=a0.z; As[k0+3][lr]=a0.w;
            As[k0+4][lr]=a1.x; As[k0+5][lr]=a1.y; As[k0+6][lr]=a1.z; As[k0+7][lr]=a1.w;
            Bs[k0+0][lr]=b0.x; Bs[k0+1][lr]=b0.y; Bs[k0+2][lr]=b0.z; Bs[k0+3][lr]=b0.w;
            Bs[k0+4][lr]=b1.x; Bs[k0+5][lr]=b1.y; Bs[k0+6][lr]=b1.z; Bs[k0+7][lr]=b1.w;
        }
        __syncthreads();
#pragma unroll
        for (int k = 0; k < 16; k++) {
            const float4 av0 = *(const float4*)&As[k][ty << 3];
            const float4 av1 = *(const float4*)&As[k][(ty << 3) + 4];
            const float4 bv0 = *(const float4*)&Bs[k][tx << 3];
            const float4 bv1 = *(const float4*)&Bs[k][(tx << 3) + 4];
            const float a[8] = {av0.x, av0.y, av0.z, av0.w, av1.x, av1.y, av1.z, av1.w};
            const float b[8] = {bv0.x, bv0.y, bv0.z, bv0.w, bv1.x, bv1.y, bv1.z, bv1.w};
#pragma unroll
            for (int r = 0; r < 8; r++)
#pragma unroll
                for (int c = 0; c < 8; c++) acc[r][c] = fmaf(a[r], b[c], acc[r][c]);
        }
    }
#pragma unroll
    for (int r = 0; r < 8; r++) {
        float4 o0 = {acc[r][0], acc[r][1], acc[r][2], acc[r][3]};
        float4 o1 = {acc[r][4], acc[r][5], acc[r][6], acc[r][7]};
        float* cp = Cm + ((size_t)(rowbase + (ty << 3) + r)) * 256 + colbase + (tx << 3);
        *(float4*)cp = o0; *(float4*)(cp + 4) = o1;
    }
}

// Normalize z rows and scatter into permuted channel layout (z_LND and f_rest)
__global__ void k_scatter(const float* __restrict__ z, const int* __restrict__ ichans,
                          float* __restrict__ zlnd, float* __restrict__ frest) {
    __shared__ float sb[4];
    const int row = blockIdx.x;            // b*1024 + n
    const int b = row >> 10, n = row & 1023;
    const int t = n >> 6, c = n & 63;
    const int o = threadIdx.x;
    const float x = z[(size_t)row * D_DIM + o];
    const float ss = blk_reduce_sum(x * x, sb);
    const float sc = 1.0f / fmaxf(sqrtf(ss), 1e-12f);
    const int ch = ichans[b * 1024 + c];
    const size_t dst = ((size_t)((b * T_DIM + t) * 64 + ch)) * D_DIM + o;
    const float val = x * sc;
    zlnd[dst] = val; frest[dst] = val;
}

// q[r] = l2norm(mean over s channels of f_rest); one block per row r = l*g + j
__global__ void k_groupq(const float* __restrict__ frest, float* __restrict__ q,
                         int g, int s) {
    __shared__ float sb[4];
    const int r = blockIdx.x;
    const int l = r / g, j = r - l * g;
    const int o = threadIdx.x;
    const float* base = frest + ((size_t)l * 64 + (size_t)j * s) * D_DIM + o;
    float acc = 0.f;
    for (int cc = 0; cc < s; cc++) acc += base[(size_t)cc * D_DIM];
    acc *= (1.0f / (float)s);
    const float ss = blk_reduce_sum(acc * acc, sb);
    const float sc = 1.0f / fmaxf(sqrtf(ss), 1e-12f);
    q[(size_t)r * D_DIM + o] = acc * sc;
}

// Fused GEMM + per-chunk top-2 argmax.  grid (R/128, NC), 256 threads.
__global__ __launch_bounds__(256) void k_argmax(
    const float* __restrict__ q, const float* __restrict__ en,
    float* __restrict__ pm1, int* __restrict__ pi1,
    float* __restrict__ pm2, int* __restrict__ pi2,
    int NC, int colsPerChunk) {
    __shared__ __align__(16) float smem[4096];
    float (*As)[128] = (float (*)[128])smem;
    float (*Bs)[128] = (float (*)[128])(smem + 2048);
    const int tid = threadIdx.x, tx = tid & 15, ty = tid >> 4;
    const int rowbase = blockIdx.x * 128;
    const int chunk = blockIdx.y;
    const int colbase0 = chunk * colsPerChunk;

    float b1[8], b2[8]; int i1[8], i2[8];
#pragma unroll
    for (int r = 0; r < 8; r++) { b1[r] = -3e38f; b2[r] = -3e38f; i1[r] = 0x7fffffff; i2[r] = 0x7fffffff; }

    for (int ct = 0; ct < colsPerChunk; ct += 128) {
        const int colbase = colbase0 + ct;
        float acc[8][8];
#pragma unroll
        for (int r = 0; r < 8; r++)
#pragma unroll
            for (int c = 0; c < 8; c++) acc[r][c] = 0.f;
        for (int kb = 0; kb < 256; kb += 16) {
            __syncthreads();
            {
                const int lr = tid >> 1, k0 = (tid & 1) << 3;
                const float4* ap = (const float4*)(q + ((size_t)(rowbase + lr)) * 256 + kb + k0);
                const float4 a0 = ap[0], a1 = ap[1];
                const float4* bp = (const float4*)(en + ((size_t)(colbase + lr)) * 256 + kb + k0);
                const float4 b0 = bp[0], b1v = bp[1];
                As[k0+0][lr]=a0.x; As[k0+1][lr]=a0.y; As[k0+2][lr]=a0.z; As[k0+3][lr]=a0.w;
                As[k0+4][lr]=a1.x; As[k0+5][lr]=a1.y; As[k0+6][lr]=a1.z; As[k0+7][lr]=a1.w;
                Bs[k0+0][lr]=b0.x; Bs[k0+1][lr]=b0.y; Bs[k0+2][lr]=b0.z; Bs[k0+3][lr]=b0.w;
                Bs[k0+4][lr]=b1v.x; Bs[k0+5][lr]=b1v.y; Bs[k0+6][lr]=b1v.z; Bs[k0+7][lr]=b1v.w;
            }
            __syncthreads();
#pragma unroll
            for (int k = 0; k < 16; k++) {
                const float4 av0 = *(const float4*)&As[k][ty << 3];
                const float4 av1 = *(const float4*)&As[k][(ty << 3) + 4];
                const float4 bv0 = *(const float4*)&Bs[k][tx << 3];
                const float4 bv1 = *(const float4*)&Bs[k][(tx << 3) + 4];
                const float a[8] = {av0.x, av0.y, av0.z, av0.w, av1.x, av1.y, av1.z, av1.w};
                const float b[8] = {bv0.x, bv0.y, bv0.z, bv0.w, bv1.x, bv1.y, bv1.z, bv1.w};
#pragma unroll
                for (int r = 0; r < 8; r++)
#pragma unroll
                    for (int c = 0; c < 8; c++) acc[r][c] = fmaf(a[r], b[c], acc[r][c]);
            }
        }
#pragma unroll
        for (int r = 0; r < 8; r++) {
#pragma unroll
            for (int c = 0; c < 8; c++) {
                const float v = acc[r][c];
                const int col = colbase + (tx << 3) + c;
                if (v > b1[r] || (v == b1[r] && col < i1[r])) {
                    b2[r] = b1[r]; i2[r] = i1[r]; b1[r] = v; i1[r] = col;
                } else if (v > b2[r] || (v == b2[r] && col < i2[r])) {
                    b2[r] = v; i2[r] = col;
                }
            }
        }
    }
    // butterfly top-2 merge across the 16 lanes sharing each row
#pragma unroll
    for (int r = 0; r < 8; r++) {
        for (int d = 1; d < 16; d <<= 1) {
            const float ov1 = __shfl_xor(b1[r], d, 64); const int oi1 = __shfl_xor(i1[r], d, 64);
            const float ov2 = __shfl_xor(b2[r], d, 64); const int oi2 = __shfl_xor(i2[r], d, 64);
            float n1, n2; int ni1, ni2;
            const bool w = (ov1 > b1[r]) || (ov1 == b1[r] && oi1 < i1[r]);
            if (w) {
                n1 = ov1; ni1 = oi1;
                const bool w2 = (b1[r] > ov2) || (b1[r] == ov2 && i1[r] < oi2);
                if (w2) { n2 = b1[r]; ni2 = i1[r]; } else { n2 = ov2; ni2 = oi2; }
            } else {
                n1 = b1[r]; ni1 = i1[r];
                const bool w2 = (ov1 > b2[r]) || (ov1 == b2[r] && oi1 < i2[r]);
                if (w2) { n2 = ov1; ni2 = oi1; } else { n2 = b2[r]; ni2 = i2[r]; }
            }
            b1[r] = n1; i1[r] = ni1; b2[r] = n2; i2[r] = ni2;
        }
        if (tx == 0) {
            const size_t row = (size_t)(rowbase + (ty << 3) + r);
            pm1[row * NC + chunk] = b1[r]; pi1[row * NC + chunk] = i1[r];
            pm2[row * NC + chunk] = b2[r]; pi2[row * NC + chunk] = i2[r];
        }
    }
}

// Merge chunk top-2s; fp64 rescore when ambiguous; write idx + counts
__global__ void k_amax_reduce(const float* __restrict__ pm1, const int* __restrict__ pi1,
                              const float* __restrict__ pm2, const int* __restrict__ pi2,
                              const float* __restrict__ q, const float* __restrict__ en,
                              int* __restrict__ idxout, float* __restrict__ counts,
                              int R, int NC) {
    const int r = blockIdx.x * 256 + threadIdx.x;
    if (r >= R) return;
    float b1 = -3e38f, b2 = -3e38f; int i1 = 0x7fffffff, i2 = 0x7fffffff;
    for (int c = 0; c < NC; c++) {
        const float cv1 = pm1[(size_t)r * NC + c]; const int ci1 = pi1[(size_t)r * NC + c];
        const float cv2 = pm2[(size_t)r * NC + c]; const int ci2 = pi2[(size_t)r * NC + c];
        const bool w = (cv1 > b1) || (cv1 == b1 && ci1 < i1);
        if (w) {
            const bool w2 = (b1 > cv2) || (b1 == cv2 && i1 < ci2);
            if (w2) { b2 = b1; i2 = i1; } else { b2 = cv2; i2 = ci2; }
            b1 = cv1; i1 = ci1;
        } else {
            const bool w2 = (cv1 > b2) || (cv1 == b2 && ci1 < i2);
            if (w2) { b2 = cv1; i2 = ci1; }
        }
    }
    int chosen = i1;
    if (b1 - b2 < 1e-4f) {
        // fp64 rescore of all chunk candidates
        double bestv = -1e300; int besti = 0x7fffffff;
        const float* qp = q + (size_t)r * 256;
        for (int c = 0; c < NC; c++) {
            for (int h = 0; h < 2; h++) {
                const int ii = h ? pi2[(size_t)r * NC + c] : pi1[(size_t)r * NC + c];
                const float* ep = en + (size_t)ii * 256;
                double s = 0.0;
                for (int k = 0; k < 256; k++) s += (double)qp[k] * (double)ep[k];
                if (s > bestv || (s == bestv && ii < besti)) { bestv = s; besti = ii; }
            }
        }
        chosen = besti;
    }
    idxout[r] = chosen;
    atomicAdd(&counts[chosen], 1.0f);
}

// f_rest -= 0.5*u + 0.5*(conv(h) + bias), using precomputed E_sum/E_0/E_2 gathers
__global__ void k_epilogue(float* __restrict__ frest, const float* __restrict__ en,
                           const float* __restrict__ esum, const float* __restrict__ e0,
                           const float* __restrict__ e2, const float* __restrict__ bias,
                           const int* __restrict__ idx, int g, int slog, int smask) {
    const int row = blockIdx.x;            // l*64 + ch
    const int l = row >> 6, ch = row & 63;
    const int j = ch >> slog;
    const int r = l * g + j;
    const int i0 = idx[r];
    const int o = threadIdx.x;
    const size_t b0 = (size_t)i0 * D_DIM + o;
    float v = 0.5f * en[b0] + 0.5f * (esum[b0] + bias[o]);
    const int chs = ch & smask;
    if (chs == 0) {
        float t = -e0[b0];
        if (j > 0) t += e0[(size_t)idx[r - 1] * D_DIM + o];
        v += 0.5f * t;
    }
    if (chs == smask) {
        float t = -e2[b0];
        if (j < g - 1) t += e2[(size_t)idx[r + 1] * D_DIM + o];
        v += 0.5f * t;
    }
    frest[(size_t)row * D_DIM + o] -= v;
}

// Sum of f_rest^2 into per-stage double accumulator
__global__ void k_loss(const float* __restrict__ frest, double* __restrict__ acc) {
    __shared__ float sb[4];
    float s = 0.f;
    for (size_t i = (size_t)blockIdx.x * 256 + threadIdx.x; i < (size_t)NELEM;
         i += (size_t)gridDim.x * 256) {
        const float x = frest[i];
        s = fmaf(x, x, s);
    }
    const float bs = blk_reduce_sum(s, sb);
    if (threadIdx.x == 0) atomicAdd(acc, (double)bs);
}

// z_q = gather(z_LND - f_rest) back through the channel permutation
__global__ void k_zq(const float* __restrict__ zlnd, const float* __restrict__ frest,
                     const int* __restrict__ ichans, float* __restrict__ out) {
    const int row = blockIdx.x;            // b*1024 + n
    const int b = row >> 10, n = row & 1023;
    const int t = n >> 6, c = n & 63;
    const int ch = ichans[b * 1024 + c];
    const size_t src = ((size_t)((b * T_DIM + t) * 64 + ch)) * D_DIM + threadIdx.x;
    out[(size_t)row * D_DIM + threadIdx.x] = zlnd[src] - frest[src];
}

// Write idx_all (as float), cluster_size_new, and loss
__global__ void k_final(const int* __restrict__ idxi, const float* __restrict__ counts,
                        const float* __restrict__ csin, const double* __restrict__ lossacc,
                        float* __restrict__ out) {
    const int i = blockIdx.x * 256 + threadIdx.x;
    if (i < 87040) {
        const int l = i / 85, t = i - l * 85;
        int v;
        if (t == 0)       v = idxi[l];
        else if (t < 5)   v = idxi[1024 + l * 4 + (t - 1)];
        else if (t < 21)  v = idxi[5120 + l * 16 + (t - 5)];
        else              v = idxi[21504 + l * 64 + (t - 21)];
        out[OUT_IDX + i] = (float)v;
    } else if (i < 87040 + 8192) {
        const int v = i - 87040;
        out[OUT_CS + v] = 0.99f * csin[v] + 0.01f * counts[v];
    } else if (i == 87040 + 8192) {
        const double s = lossacc[0] + lossacc[1] + lossacc[2] + lossacc[3];
        out[OUT_LOSS] = (float)(s * (1.25 / 4.0) / 16777216.0);
    }
}

extern "C" void kernel_launch(void* const* d_in, const int* in_sizes, int n_in,
                              void* d_out, int out_size, void* d_ws, size_t ws_size,
                              hipStream_t stream) {
    (void)in_sizes; (void)n_in; (void)out_size; (void)ws_size;
    const float* z      = (const float*)d_in[0];
    const int*   ichans = (const int*)d_in[1];
    // d_in[2] = input_time (unused by reference)
    const float* emb    = (const float*)d_in[3];
    const float* phiw   = (const float*)d_in[4];
    const float* phib   = (const float*)d_in[5];
    const float* csin   = (const float*)d_in[6];
    float* ws  = (float*)d_ws;
    float* out = (float*)d_out;

    float* en    = ws + EN_OFF;
    float* esum  = ws + ESUM_OFF;
    float* e0    = ws + E0_OFF;
    float* e2    = ws + E2_OFF;
    float* wsum  = ws + WSUM_OFF;
    float* w0    = ws + W0_OFF;
    float* w2    = ws + W2_OFF;
    float* zlnd  = ws + ZLND_OFF;
    float* frest = ws + FREST_OFF;
    float* qbuf  = ws + Q_OFF;
    float* pm1   = ws + PM1_OFF;
    int*   pi1   = (int*)(ws + PI1_OFF);
    float* pm2   = ws + PM2_OFF;
    int*   pi2   = (int*)(ws + PI2_OFF);
    int*   idxi  = (int*)(ws + IDXI_OFF);
    float* counts = ws + CNT_OFF;
    double* lossacc = (double*)(ws + LOSS_OFF);

    // zero counts (8192 f32) + loss accumulators (4 doubles), contiguous
    hipMemsetAsync(counts, 0, 8192 * sizeof(float) + 4 * sizeof(double), stream);

    k_norm_embed<<<V_DIM, 256, 0, stream>>>(emb, en);
    k_prep_w<<<256, 256, 0, stream>>>(phiw, wsum, w0, w2);
    k_phi_gemm<<<dim3(V_DIM / 128, 2, 3), 256, 0, stream>>>(en, wsum, w0, w2, esum, e0, e2);
    k_scatter<<<NROW, 256, 0, stream>>>(z, ichans, zlnd, frest);

    const int gs[4]   = {1, 4, 16, 64};
    const int ncs[4]  = {64, 16, 8, 4};
    const int offs[4] = {0, 1024, 5120, 21504};
    const int slogs[4] = {6, 4, 2, 0};
    for (int st = 0; st < 4; st++) {
        const int g = gs[st], s = 64 / g, NC = ncs[st], R = L_DIM * g;
        k_groupq<<<R, 256, 0, stream>>>(frest, qbuf, g, s);
        k_argmax<<<dim3(R / 128, NC), 256, 0, stream>>>(qbuf, en, pm1, pi1, pm2, pi2,
                                                        NC, V_DIM / NC);
        k_amax_reduce<<<(R + 255) / 256, 256, 0, stream>>>(pm1, pi1, pm2, pi2, qbuf, en,
                                                           idxi + offs[st], counts, R, NC);
        k_epilogue<<<NROW, 256, 0, stream>>>(frest, en, esum, e0, e2, phib,
                                             idxi + offs[st], g, slogs[st], s - 1);
        k_loss<<<2048, 256, 0, stream>>>(frest, lossacc + st);
    }

    k_zq<<<NROW, 256, 0, stream>>>(zlnd, frest, ichans, out);
    k_final<<<373, 256, 0, stream>>>(idxi, counts, csin, lossacc, out);
}

// Round 3
// 2961.669 us; speedup vs baseline: 2.3223x; 2.3223x over previous
//
#include <hip/hip_runtime.h>

// Problem constants
#define D_DIM 256
#define V_DIM 8192
#define L_DIM 1024          // B*T
#define NROW 65536          // L*64 rows of f_rest
#define NELEM 16777216      // NROW * D

// Output layout (all float32 in d_out)
#define OUT_LOSS 16777216
#define OUT_IDX  16777217
#define OUT_CS   16864257

// Workspace float offsets
#define EN_OFF    ((size_t)0)
#define ENH_OFF   ((size_t)2097152)
#define ESUM_OFF  ((size_t)3145728)
#define E0_OFF    ((size_t)5242880)
#define E2_OFF    ((size_t)7340032)
#define WSUM_OFF  ((size_t)9437184)
#define W0_OFF    ((size_t)9502720)
#define W2_OFF    ((size_t)9568256)
#define FREST_OFF ((size_t)9633792)
#define QF_OFF    ((size_t)26411008)
#define QH_OFF    ((size_t)43188224)
#define PTOP_OFF  ((size_t)51576832)
#define IDXI_OFF  ((size_t)52625408)
#define CNT_OFF   ((size_t)52712448)
#define LOSSP_OFF ((size_t)52720640)
#define RNORM_OFF ((size_t)52722688)
#define INV_OFF   ((size_t)52788224)

typedef __attribute__((ext_vector_type(8))) short bf16x8;
typedef __attribute__((ext_vector_type(4))) float f32x4;

__device__ __forceinline__ unsigned int umaxu(unsigned int a, unsigned int b) { return a > b ? a : b; }
__device__ __forceinline__ unsigned int uminu(unsigned int a, unsigned int b) { return a < b ? a : b; }

__device__ __forceinline__ unsigned short f2b(float x) {
    unsigned int u = __float_as_uint(x);
    unsigned int r = (u + 0x7FFFu + ((u >> 16) & 1u)) >> 16;   // RNE
    return (unsigned short)r;
}

__device__ __forceinline__ void gl_lds16(const void* g, void* l) {
    __builtin_amdgcn_global_load_lds(
        (const __attribute__((address_space(1))) unsigned int*)g,
        (__attribute__((address_space(3))) unsigned int*)l, 16, 0, 0);
}

__device__ __forceinline__ float blk_reduce_sum(float v, float* sb) {
#pragma unroll
    for (int off = 32; off; off >>= 1) v += __shfl_down(v, off, 64);
    const int w = threadIdx.x >> 6;
    if ((threadIdx.x & 63) == 0) sb[w] = v;
    __syncthreads();
    return sb[0] + sb[1] + sb[2] + sb[3];
}

// Normalize embedding rows: en = emb / max(||emb||,1e-12), also emit bf16 copy
__global__ void k_norm_embed(const float* __restrict__ emb, float* __restrict__ en,
                             unsigned short* __restrict__ enh) {
    __shared__ float sb[4];
    const int v = blockIdx.x, o = threadIdx.x;
    const float x = emb[(size_t)v * 256 + o];
    const float ss = blk_reduce_sum(x * x, sb);
    const float sc = 1.0f / fmaxf(sqrtf(ss), 1e-12f);
    const float y = x * sc;
    en[(size_t)v * 256 + o] = y;
    enh[(size_t)v * 256 + o] = f2b(y);
}

// Repack phi_w (D,D,3) into Wsum / W0 / W2, each (o,i) row-major
__global__ void k_prep_w(const float* __restrict__ pw, float* __restrict__ wsum,
                         float* __restrict__ w0, float* __restrict__ w2) {
    const int i = blockIdx.x * 256 + threadIdx.x;
    const float a = pw[(size_t)i * 3 + 0];
    const float b = pw[(size_t)i * 3 + 1];
    const float c = pw[(size_t)i * 3 + 2];
    wsum[i] = a + b + c; w0[i] = a; w2[i] = c;
}

// E_k = e_n @ Wk^T (fp32 — feeds values, keep precision). grid (64, 2, 3)
__global__ __launch_bounds__(256) void k_phi_gemm(
    const float* __restrict__ en, const float* __restrict__ wsum,
    const float* __restrict__ w0, const float* __restrict__ w2,
    float* __restrict__ esum, float* __restrict__ e0, float* __restrict__ e2) {
    __shared__ __align__(16) float smem[4096];
    float (*As)[128] = (float (*)[128])smem;
    float (*Bs)[128] = (float (*)[128])(smem + 2048);
    const float* Bm; float* Cm;
    if (blockIdx.z == 0)      { Bm = wsum; Cm = esum; }
    else if (blockIdx.z == 1) { Bm = w0;   Cm = e0;   }
    else                      { Bm = w2;   Cm = e2;   }
    const int tid = threadIdx.x, tx = tid & 15, ty = tid >> 4;
    const int rowbase = blockIdx.x * 128, colbase = blockIdx.y * 128;
    float acc[8][8];
#pragma unroll
    for (int r = 0; r < 8; r++)
#pragma unroll
        for (int c = 0; c < 8; c++) acc[r][c] = 0.f;
    for (int kb = 0; kb < 256; kb += 16) {
        __syncthreads();
        {
            const int lr = tid >> 1, k0 = (tid & 1) << 3;
            const float4* ap = (const float4*)(en + ((size_t)(rowbase + lr)) * 256 + kb + k0);
            const float4 a0 = ap[0], a1 = ap[1];
            const float4* bp = (const float4*)(Bm + ((size_t)(colbase + lr)) * 256 + kb + k0);
            const float4 b0 = bp[0], b1 = bp[1];
            As[k0+0][lr]=a0.x; As[k0+1][lr]=a0.y; As[k0+2][lr]=a0.z; As[k0+3][lr]=a0.w;
            As[k0+4][lr]=a1.x; As[k0+5][lr]=a1.y; As[k0+6][lr]=a1.z; As[k0+7][lr]=a1.w;
            Bs[k0+0][lr]=b0.x; Bs[k0+1][lr]=b0.y; Bs[k0+2][lr]=b0.z; Bs[k0+3][lr]=b0.w;
            Bs[k0+4][lr]=b1.x; Bs[k0+5][lr]=b1.y; Bs[k0+6][lr]=b1.z; Bs[k0+7][lr]=b1.w;
        }
        __syncthreads();
#pragma unroll
        for (int k = 0; k < 16; k++) {
            const float4 av0 = *(const float4*)&As[k][ty << 3];
            const float4 av1 = *(const float4*)&As[k][(ty << 3) + 4];
            const float4 bv0 = *(const float4*)&Bs[k][tx << 3];
            const float4 bv1 = *(const float4*)&Bs[k][(tx << 3) + 4];
            const float a[8] = {av0.x, av0.y, av0.z, av0.w, av1.x, av1.y, av1.z, av1.w};
            const float b[8] = {bv0.x, bv0.y, bv0.z, bv0.w, bv1.x, bv1.y, bv1.z, bv1.w};
#pragma unroll
            for (int r = 0; r < 8; r++)
#pragma unroll
                for (int c = 0; c < 8; c++) acc[r][c] = fmaf(a[r], b[c], acc[r][c]);
        }
    }
#pragma unroll
    for (int r = 0; r < 8; r++) {
        float4 o0 = {acc[r][0], acc[r][1], acc[r][2], acc[r][3]};
        float4 o1 = {acc[r][4], acc[r][5], acc[r][6], acc[r][7]};
        float* cp = Cm + ((size_t)(rowbase + (ty << 3) + r)) * 256 + colbase + (tx << 3);
        *(float4*)cp = o0; *(float4*)(cp + 4) = o1;
    }
}

// inverse channel permutation: inv[b][ch] = c
__global__ void k_invperm(const int* __restrict__ ichans, int* __restrict__ inv) {
    const int b = blockIdx.x, c = threadIdx.x;
    inv[(b << 6) + ichans[(b << 10) + c]] = c;
}

// Normalize z rows, scatter into permuted layout (frest), save 1/||z|| per row
__global__ void k_scatter(const float* __restrict__ z, const int* __restrict__ ichans,
                          float* __restrict__ frest, float* __restrict__ rnorm) {
    __shared__ float sb[4];
    const int zrow = blockIdx.x;
    const int b = zrow >> 10, n = zrow & 1023;
    const int t = n >> 6, c = n & 63;
    const int o = threadIdx.x;
    const float x = z[(size_t)zrow * 256 + o];
    const float ss = blk_reduce_sum(x * x, sb);
    const float sc = 1.0f / fmaxf(sqrtf(ss), 1e-12f);
    const int ch = ichans[(b << 10) + c];
    frest[((size_t)(((b << 4) + t) * 64 + ch)) * 256 + o] = x * sc;
    if (o == 0) rnorm[zrow] = sc;
}

// q[r] = l2norm(mean over s channels of frest); emit fp32 + bf16
__global__ void k_groupq(const float* __restrict__ frest, float* __restrict__ qf,
                         unsigned short* __restrict__ qh, int g, int s) {
    __shared__ float sb[4];
    const int r = blockIdx.x;
    const int l = r / g, j = r - l * g;
    const int o = threadIdx.x;
    const float* base = frest + ((size_t)l * 64 + (size_t)j * s) * 256 + o;
    float acc = 0.f;
    for (int cc = 0; cc < s; cc++) acc += base[(size_t)cc * 256];
    acc *= (1.0f / (float)s);
    const float ss = blk_reduce_sum(acc * acc, sb);
    const float sc = 1.0f / fmaxf(sqrtf(ss), 1e-12f);
    const float qv = acc * sc;
    qf[(size_t)r * 256 + o] = qv;
    qh[(size_t)r * 256 + o] = f2b(qv);
}

// bf16 MFMA GEMM + packed per-chunk top-2. grid (R/128, NC), 256 threads.
// 128x128 tile, 4 waves as 2x2 (wr,wc) of 64x64; BK=32.
// The two wc waves cover the SAME rows, different column halves -> must be
// merged via LDS before the single ptop write (R2's race bug fixed here).
__global__ __launch_bounds__(256, 3) void k_amax1(
    const unsigned short* __restrict__ qh, const unsigned short* __restrict__ enh,
    uint2* __restrict__ ptop, int NC, int colsPerChunk) {
    __shared__ unsigned short As[4096];   // [row 0..127][k 0..31], 64B row stride
    __shared__ unsigned short Bs[4096];
    const int tid = threadIdx.x;
    const int lane = tid & 63;
    const int m = lane & 15, q4 = lane >> 4;
    const int w = tid >> 6;
    const int wr = w >> 1, wc = w & 1;
    const int rowbase = blockIdx.x * 128;
    const int chunk = blockIdx.y;
    const int srow = tid >> 2, sgr = tid & 3;

    const unsigned short* qa0 = qh + (size_t)(rowbase + srow) * 256 + sgr * 8;
    const unsigned short* qa1 = qa0 + 64 * 256;
    unsigned short* lA0 = &As[tid * 8];
    unsigned short* lA1 = &As[2048 + tid * 8];
    unsigned short* lB0 = &Bs[tid * 8];
    unsigned short* lB1 = &Bs[2048 + tid * 8];

    unsigned int t1[4][4], t2[4][4];
#pragma unroll
    for (int i = 0; i < 4; i++)
#pragma unroll
        for (int r = 0; r < 4; r++) { t1[i][r] = 0u; t2[i][r] = 0u; }

    const int ntiles = colsPerChunk >> 7;
    for (int nt = 0; nt < ntiles; nt++) {
        const int colchunk = chunk * colsPerChunk + nt * 128;
        const unsigned short* ba0 = enh + (size_t)(colchunk + srow) * 256 + sgr * 8;
        const unsigned short* ba1 = ba0 + 64 * 256;
        f32x4 acc[4][4];
#pragma unroll
        for (int i = 0; i < 4; i++)
#pragma unroll
            for (int j = 0; j < 4; j++) acc[i][j] = (f32x4){0.f, 0.f, 0.f, 0.f};

        for (int kb = 0; kb < 256; kb += 32) {
            __syncthreads();
            gl_lds16(qa0 + kb, lA0);
            gl_lds16(qa1 + kb, lA1);
            gl_lds16(ba0 + kb, lB0);
            gl_lds16(ba1 + kb, lB1);
            __syncthreads();
            bf16x8 af[4], bfr[4];
#pragma unroll
            for (int i = 0; i < 4; i++)
                af[i] = *(const bf16x8*)&As[(wr * 64 + i * 16 + m) * 32 + q4 * 8];
#pragma unroll
            for (int j = 0; j < 4; j++)
                bfr[j] = *(const bf16x8*)&Bs[(wc * 64 + j * 16 + m) * 32 + q4 * 8];
#pragma unroll
            for (int i = 0; i < 4; i++)
#pragma unroll
                for (int j = 0; j < 4; j++)
                    acc[i][j] = __builtin_amdgcn_mfma_f32_16x16x32_bf16(af[i], bfr[j], acc[i][j], 0, 0, 0);
        }
        // packed top-2 update: pack = bits(v+1.25) & ~0x1FFF | (8191-col)
#pragma unroll
        for (int j = 0; j < 4; j++) {
            const unsigned int ct = 8191u - (unsigned int)(colchunk + wc * 64 + j * 16 + m);
#pragma unroll
            for (int i = 0; i < 4; i++)
#pragma unroll
                for (int r = 0; r < 4; r++) {
                    const float wv = acc[i][j][r] + 1.25f;
                    const unsigned int cand = (__float_as_uint(wv) & 0xFFFFE000u) | ct;
                    const unsigned int nb1 = umaxu(t1[i][r], cand);
                    t2[i][r] = umaxu(t2[i][r], uminu(t1[i][r], cand));
                    t1[i][r] = nb1;
                }
        }
    }
    // butterfly top-2 merge across the 16 lanes of each quad
    unsigned int mb1[4][4], mb2[4][4];
#pragma unroll
    for (int i = 0; i < 4; i++)
#pragma unroll
        for (int r = 0; r < 4; r++) {
            unsigned int b1 = t1[i][r], b2 = t2[i][r];
#pragma unroll
            for (int d = 1; d < 16; d <<= 1) {
                const unsigned int o1 = (unsigned int)__shfl_xor((int)b1, d, 64);
                const unsigned int o2 = (unsigned int)__shfl_xor((int)b2, d, 64);
                const unsigned int mn = uminu(b1, o1);
                b1 = umaxu(b1, o1);
                b2 = umaxu(mn, umaxu(b2, o2));
            }
            mb1[i][r] = b1; mb2[i][r] = b2;
        }
    // cross-wave merge: wc=1 deposits to LDS, wc=0 merges + writes
    __syncthreads();                       // all As reads done before reuse
    uint2* msh = (uint2*)As;               // 128 rows x uint2 (1 KB)
    if (wc == 1 && m == 0) {
#pragma unroll
        for (int i = 0; i < 4; i++)
#pragma unroll
            for (int r = 0; r < 4; r++)
                msh[wr * 64 + i * 16 + q4 * 4 + r] = make_uint2(mb1[i][r], mb2[i][r]);
    }
    __syncthreads();
    if (wc == 0 && m == 0) {
#pragma unroll
        for (int i = 0; i < 4; i++)
#pragma unroll
            for (int r = 0; r < 4; r++) {
                const int rl = wr * 64 + i * 16 + q4 * 4 + r;
                const uint2 o = msh[rl];
                unsigned int b1 = mb1[i][r], b2 = mb2[i][r];
                const unsigned int mn = uminu(b1, o.x);
                b1 = umaxu(b1, o.x);
                b2 = umaxu(mn, umaxu(b2, o.y));
                ptop[(size_t)(rowbase + rl) * NC + chunk] = make_uint2(b1, b2);
            }
    }
}

__device__ double score256(const float* __restrict__ qp, const float* __restrict__ ep) {
    double s = 0.0;
    for (int k = 0; k < 256; k += 4) {
        const float4 a = *(const float4*)(qp + k);
        const float4 b = *(const float4*)(ep + k);
        s += (double)a.x * b.x + (double)a.y * b.y + (double)a.z * b.z + (double)a.w * b.w;
    }
    return s;
}

// Merge per-chunk packed top-2; fp64 rescore (top-2 always, all 2NC when ambiguous)
__global__ void k_amax2(const uint2* __restrict__ ptop, const float* __restrict__ qf,
                        const float* __restrict__ en, int* __restrict__ idxout,
                        float* __restrict__ counts, int R, int NC) {
    const int r = blockIdx.x * 256 + threadIdx.x;
    if (r >= R) return;
    unsigned int b1 = 0u, b2 = 0u;
    const uint2* pp = ptop + (size_t)r * NC;
    for (int c = 0; c < NC; c++) {
        const uint2 p = pp[c];
        const unsigned int mn = uminu(b1, p.x);
        b1 = umaxu(b1, p.x);
        b2 = umaxu(mn, umaxu(b2, p.y));
    }
    const float* qp = qf + (size_t)r * 256;
    int best;
    if ((b1 & 0xFFFFE000u) - (b2 & 0xFFFFE000u) < 32768u) {
        double bv = -1e300; best = 0x7fffffff;
        for (int c = 0; c < NC; c++) {
            const uint2 p = pp[c];
            for (int h = 0; h < 2; h++) {
                const int col = 8191 - (int)((h ? p.y : p.x) & 0x1FFFu);
                const double s = score256(qp, en + (size_t)col * 256);
                if (s > bv || (s == bv && col < best)) { bv = s; best = col; }
            }
        }
    } else {
        const int c1 = 8191 - (int)(b1 & 0x1FFFu);
        const int c2 = 8191 - (int)(b2 & 0x1FFFu);
        const double s1 = score256(qp, en + (size_t)c1 * 256);
        const double s2 = score256(qp, en + (size_t)c2 * 256);
        best = (s2 > s1 || (s2 == s1 && c2 < c1)) ? c2 : c1;
    }
    idxout[r] = best;
    atomicAdd(&counts[best], 1.0f);
}

// frest -= 0.5*u + 0.5*(conv(h)+bias); fused loss; optional q-emit (s=1) / z_q-emit
__global__ void k_epilogue(float* __restrict__ frest, const float* __restrict__ en,
    const float* __restrict__ esum, const float* __restrict__ e0, const float* __restrict__ e2,
    const float* __restrict__ bias, const int* __restrict__ idx,
    int g, int slog, int smask, double* __restrict__ lossp,
    int emitQ, float* __restrict__ qf, unsigned short* __restrict__ qh,
    int emitOut, const float* __restrict__ z, const float* __restrict__ rnorm,
    const int* __restrict__ inv, float* __restrict__ out) {
    __shared__ float sb[4];
    const int row = blockIdx.x;
    const int l = row >> 6, ch = row & 63;
    const int j = ch >> slog;
    const int r = l * g + j;
    const int i0 = idx[r];
    const int o = threadIdx.x;
    const size_t b0 = (size_t)i0 * 256 + o;
    float v = 0.5f * en[b0] + 0.5f * (esum[b0] + bias[o]);
    const int chs = ch & smask;
    if (chs == 0) {
        float t = -e0[b0];
        if (j > 0) t += e0[(size_t)idx[r - 1] * 256 + o];
        v += 0.5f * t;
    }
    if (chs == smask) {
        float t = -e2[b0];
        if (j < g - 1) t += e2[(size_t)idx[r + 1] * 256 + o];
        v += 0.5f * t;
    }
    const float nv = frest[(size_t)row * 256 + o] - v;
    const float ss = blk_reduce_sum(nv * nv, sb);
    if (o == 0) atomicAdd(&lossp[blockIdx.x & 255], (double)ss);
    if (emitOut) {
        const int b = l >> 4, t_ = l & 15;
        const int c = inv[(b << 6) + ch];
        const size_t zr = (size_t)((b << 10) + (t_ << 6) + c);
        out[zr * 256 + o] = z[zr * 256 + o] * rnorm[zr] - nv;   // z_q = z_LND - f_rest
    } else {
        frest[(size_t)row * 256 + o] = nv;
        if (emitQ) {   // s=1 stage: q row == normalized frest row
            const float sc = 1.0f / fmaxf(sqrtf(ss), 1e-12f);
            const float qv = nv * sc;
            qf[(size_t)row * 256 + o] = qv;
            qh[(size_t)row * 256 + o] = f2b(qv);
        }
    }
}

__global__ void k_losssum(const double* __restrict__ lossp, float* __restrict__ out) {
    __shared__ double sb[4];
    double s = 0.0;
    for (int i = threadIdx.x; i < 1024; i += 256) s += lossp[i];
#pragma unroll
    for (int off = 32; off; off >>= 1) s += __shfl_down(s, off, 64);
    if ((threadIdx.x & 63) == 0) sb[threadIdx.x >> 6] = s;
    __syncthreads();
    if (threadIdx.x == 0)
        out[OUT_LOSS] = (float)((sb[0] + sb[1] + sb[2] + sb[3]) * (1.25 / 4.0) / 16777216.0);
}

// idx_all (as float) and cluster_size_new
__global__ void k_final(const int* __restrict__ idxi, const float* __restrict__ counts,
                        const float* __restrict__ csin, float* __restrict__ out) {
    const int i = blockIdx.x * 256 + threadIdx.x;
    if (i < 87040) {
        const int l = i / 85, t = i - l * 85;
        int v;
        if (t == 0)       v = idxi[l];
        else if (t < 5)   v = idxi[1024 + l * 4 + (t - 1)];
        else if (t < 21)  v = idxi[5120 + l * 16 + (t - 5)];
        else              v = idxi[21504 + l * 64 + (t - 21)];
        out[OUT_IDX + i] = (float)v;
    } else if (i < 87040 + 8192) {
        const int v = i - 87040;
        out[OUT_CS + v] = 0.99f * csin[v] + 0.01f * counts[v];
    }
}

extern "C" void kernel_launch(void* const* d_in, const int* in_sizes, int n_in,
                              void* d_out, int out_size, void* d_ws, size_t ws_size,
                              hipStream_t stream) {
    (void)in_sizes; (void)n_in; (void)out_size; (void)ws_size;
    const float* z      = (const float*)d_in[0];
    const int*   ichans = (const int*)d_in[1];
    const float* emb    = (const float*)d_in[3];
    const float* phiw   = (const float*)d_in[4];
    const float* phib   = (const float*)d_in[5];
    const float* csin   = (const float*)d_in[6];
    float* ws  = (float*)d_ws;
    float* out = (float*)d_out;

    float* en    = ws + EN_OFF;
    unsigned short* enh = (unsigned short*)(ws + ENH_OFF);
    float* esum  = ws + ESUM_OFF;
    float* e0    = ws + E0_OFF;
    float* e2    = ws + E2_OFF;
    float* wsum  = ws + WSUM_OFF;
    float* w0    = ws + W0_OFF;
    float* w2    = ws + W2_OFF;
    float* frest = ws + FREST_OFF;
    float* qf    = ws + QF_OFF;
    unsigned short* qh = (unsigned short*)(ws + QH_OFF);
    uint2* ptop  = (uint2*)(ws + PTOP_OFF);
    int*   idxi  = (int*)(ws + IDXI_OFF);
    float* counts = ws + CNT_OFF;
    double* lossp = (double*)(ws + LOSSP_OFF);
    float* rnorm = ws + RNORM_OFF;
    int*   inv   = (int*)(ws + INV_OFF);

    // zero counts (8192 f32) + lossp (1024 doubles), contiguous
    hipMemsetAsync(counts, 0, 8192 * sizeof(float) + 1024 * sizeof(double), stream);

    k_norm_embed<<<V_DIM, 256, 0, stream>>>(emb, en, enh);
    k_prep_w<<<256, 256, 0, stream>>>(phiw, wsum, w0, w2);
    k_phi_gemm<<<dim3(V_DIM / 128, 2, 3), 256, 0, stream>>>(en, wsum, w0, w2, esum, e0, e2);
    k_invperm<<<64, 64, 0, stream>>>(ichans, inv);
    k_scatter<<<NROW, 256, 0, stream>>>(z, ichans, frest, rnorm);

    const int gs[4]    = {1, 4, 16, 64};
    const int ncs[4]   = {64, 32, 16, 8};
    const int cpcs[4]  = {128, 256, 512, 1024};
    const int offs[4]  = {0, 1024, 5120, 21504};
    const int slogs[4] = {6, 4, 2, 0};
    for (int st = 0; st < 4; st++) {
        const int g = gs[st], s = 64 / g, NC = ncs[st], R = L_DIM * g;
        if (st < 3)
            k_groupq<<<R, 256, 0, stream>>>(frest, qf, qh, g, s);
        k_amax1<<<dim3(R / 128, NC), 256, 0, stream>>>(qh, enh, ptop, NC, cpcs[st]);
        k_amax2<<<(R + 255) / 256, 256, 0, stream>>>(ptop, qf, en, idxi + offs[st], counts, R, NC);
        k_epilogue<<<NROW, 256, 0, stream>>>(frest, en, esum, e0, e2, phib, idxi + offs[st],
                                             g, slogs[st], s - 1, lossp + st * 256,
                                             (st == 2) ? 1 : 0, qf, qh,
                                             (st == 3) ? 1 : 0, z, rnorm, inv, out);
    }

    k_losssum<<<1, 256, 0, stream>>>(lossp, out);
    k_final<<<372, 256, 0, stream>>>(idxi, counts, csin, out);
}

// Round 4
// 1358.656 us; speedup vs baseline: 5.0623x; 2.1799x over previous
//
#include <hip/hip_runtime.h>

// Problem constants
#define D_DIM 256
#define V_DIM 8192
#define L_DIM 1024          // B*T
#define NROW 65536          // L*64 rows of f_rest
#define NELEM 16777216      // NROW * D

// Output layout (all float32 in d_out)
#define OUT_LOSS 16777216
#define OUT_IDX  16777217
#define OUT_CS   16864257

// Workspace float offsets
#define EN_OFF    ((size_t)0)
#define ENH_OFF   ((size_t)2097152)
#define ESUM_OFF  ((size_t)3145728)
#define E0_OFF    ((size_t)5242880)
#define E2_OFF    ((size_t)7340032)
#define WSUM_OFF  ((size_t)9437184)
#define W0_OFF    ((size_t)9502720)
#define W2_OFF    ((size_t)9568256)
#define FREST_OFF ((size_t)9633792)
#define QF_OFF    ((size_t)26411008)
#define QH_OFF    ((size_t)43188224)
#define PTOP_OFF  ((size_t)51576832)
#define IDXI_OFF  ((size_t)52625408)
#define CNT_OFF   ((size_t)52712448)
#define LOSSP_OFF ((size_t)52720640)
#define RNORM_OFF ((size_t)52722688)
#define INV_OFF   ((size_t)52788224)

typedef __attribute__((ext_vector_type(8))) short bf16x8;
typedef __attribute__((ext_vector_type(4))) float f32x4;

__device__ __forceinline__ unsigned int umaxu(unsigned int a, unsigned int b) { return a > b ? a : b; }
__device__ __forceinline__ unsigned int uminu(unsigned int a, unsigned int b) { return a < b ? a : b; }

__device__ __forceinline__ unsigned short f2b(float x) {
    unsigned int u = __float_as_uint(x);
    unsigned int r = (u + 0x7FFFu + ((u >> 16) & 1u)) >> 16;   // RNE
    return (unsigned short)r;
}

__device__ __forceinline__ void gl_lds16(const void* g, void* l) {
    __builtin_amdgcn_global_load_lds(
        (const __attribute__((address_space(1))) unsigned int*)g,
        (__attribute__((address_space(3))) unsigned int*)l, 16, 0, 0);
}

__device__ __forceinline__ float blk_reduce_sum(float v, float* sb) {
#pragma unroll
    for (int off = 32; off; off >>= 1) v += __shfl_down(v, off, 64);
    const int w = threadIdx.x >> 6;
    if ((threadIdx.x & 63) == 0) sb[w] = v;
    __syncthreads();
    return sb[0] + sb[1] + sb[2] + sb[3];
}

// Normalize embedding rows: en = emb / max(||emb||,1e-12), also emit bf16 copy
__global__ void k_norm_embed(const float* __restrict__ emb, float* __restrict__ en,
                             unsigned short* __restrict__ enh) {
    __shared__ float sb[4];
    const int v = blockIdx.x, o = threadIdx.x;
    const float x = emb[(size_t)v * 256 + o];
    const float ss = blk_reduce_sum(x * x, sb);
    const float sc = 1.0f / fmaxf(sqrtf(ss), 1e-12f);
    const float y = x * sc;
    en[(size_t)v * 256 + o] = y;
    enh[(size_t)v * 256 + o] = f2b(y);
}

// Repack phi_w (D,D,3) into Wsum / W0 / W2, each (o,i) row-major
__global__ void k_prep_w(const float* __restrict__ pw, float* __restrict__ wsum,
                         float* __restrict__ w0, float* __restrict__ w2) {
    const int i = blockIdx.x * 256 + threadIdx.x;
    const float a = pw[(size_t)i * 3 + 0];
    const float b = pw[(size_t)i * 3 + 1];
    const float c = pw[(size_t)i * 3 + 2];
    wsum[i] = a + b + c; w0[i] = a; w2[i] = c;
}

// E_k = e_n @ Wk^T (fp32 — feeds values, keep precision). grid (64, 2, 3)
__global__ __launch_bounds__(256) void k_phi_gemm(
    const float* __restrict__ en, const float* __restrict__ wsum,
    const float* __restrict__ w0, const float* __restrict__ w2,
    float* __restrict__ esum, float* __restrict__ e0, float* __restrict__ e2) {
    __shared__ __align__(16) float smem[4096];
    float (*As)[128] = (float (*)[128])smem;
    float (*Bs)[128] = (float (*)[128])(smem + 2048);
    const float* Bm; float* Cm;
    if (blockIdx.z == 0)      { Bm = wsum; Cm = esum; }
    else if (blockIdx.z == 1) { Bm = w0;   Cm = e0;   }
    else                      { Bm = w2;   Cm = e2;   }
    const int tid = threadIdx.x, tx = tid & 15, ty = tid >> 4;
    const int rowbase = blockIdx.x * 128, colbase = blockIdx.y * 128;
    float acc[8][8];
#pragma unroll
    for (int r = 0; r < 8; r++)
#pragma unroll
        for (int c = 0; c < 8; c++) acc[r][c] = 0.f;
    for (int kb = 0; kb < 256; kb += 16) {
        __syncthreads();
        {
            const int lr = tid >> 1, k0 = (tid & 1) << 3;
            const float4* ap = (const float4*)(en + ((size_t)(rowbase + lr)) * 256 + kb + k0);
            const float4 a0 = ap[0], a1 = ap[1];
            const float4* bp = (const float4*)(Bm + ((size_t)(colbase + lr)) * 256 + kb + k0);
            const float4 b0 = bp[0], b1 = bp[1];
            As[k0+0][lr]=a0.x; As[k0+1][lr]=a0.y; As[k0+2][lr]=a0.z; As[k0+3][lr]=a0.w;
            As[k0+4][lr]=a1.x; As[k0+5][lr]=a1.y; As[k0+6][lr]=a1.z; As[k0+7][lr]=a1.w;
            Bs[k0+0][lr]=b0.x; Bs[k0+1][lr]=b0.y; Bs[k0+2][lr]=b0.z; Bs[k0+3][lr]=b0.w;
            Bs[k0+4][lr]=b1.x; Bs[k0+5][lr]=b1.y; Bs[k0+6][lr]=b1.z; Bs[k0+7][lr]=b1.w;
        }
        __syncthreads();
#pragma unroll
        for (int k = 0; k < 16; k++) {
            const float4 av0 = *(const float4*)&As[k][ty << 3];
            const float4 av1 = *(const float4*)&As[k][(ty << 3) + 4];
            const float4 bv0 = *(const float4*)&Bs[k][tx << 3];
            const float4 bv1 = *(const float4*)&Bs[k][(tx << 3) + 4];
            const float a[8] = {av0.x, av0.y, av0.z, av0.w, av1.x, av1.y, av1.z, av1.w};
            const float b[8] = {bv0.x, bv0.y, bv0.z, bv0.w, bv1.x, bv1.y, bv1.z, bv1.w};
#pragma unroll
            for (int r = 0; r < 8; r++)
#pragma unroll
                for (int c = 0; c < 8; c++) acc[r][c] = fmaf(a[r], b[c], acc[r][c]);
        }
    }
#pragma unroll
    for (int r = 0; r < 8; r++) {
        float4 o0 = {acc[r][0], acc[r][1], acc[r][2], acc[r][3]};
        float4 o1 = {acc[r][4], acc[r][5], acc[r][6], acc[r][7]};
        float* cp = Cm + ((size_t)(rowbase + (ty << 3) + r)) * 256 + colbase + (tx << 3);
        *(float4*)cp = o0; *(float4*)(cp + 4) = o1;
    }
}

// inverse channel permutation: inv[b][ch] = c
__global__ void k_invperm(const int* __restrict__ ichans, int* __restrict__ inv) {
    const int b = blockIdx.x, c = threadIdx.x;
    inv[(b << 6) + ichans[(b << 10) + c]] = c;
}

// Normalize z rows, scatter into permuted layout (frest), save 1/||z|| per row
__global__ void k_scatter(const float* __restrict__ z, const int* __restrict__ ichans,
                          float* __restrict__ frest, float* __restrict__ rnorm) {
    __shared__ float sb[4];
    const int zrow = blockIdx.x;
    const int b = zrow >> 10, n = zrow & 1023;
    const int t = n >> 6, c = n & 63;
    const int o = threadIdx.x;
    const float x = z[(size_t)zrow * 256 + o];
    const float ss = blk_reduce_sum(x * x, sb);
    const float sc = 1.0f / fmaxf(sqrtf(ss), 1e-12f);
    const int ch = ichans[(b << 10) + c];
    frest[((size_t)(((b << 4) + t) * 64 + ch)) * 256 + o] = x * sc;
    if (o == 0) rnorm[zrow] = sc;
}

// q[r] = l2norm(mean over s channels of frest); emit fp32 + bf16
__global__ void k_groupq(const float* __restrict__ frest, float* __restrict__ qf,
                         unsigned short* __restrict__ qh, int g, int s) {
    __shared__ float sb[4];
    const int r = blockIdx.x;
    const int l = r / g, j = r - l * g;
    const int o = threadIdx.x;
    const float* base = frest + ((size_t)l * 64 + (size_t)j * s) * 256 + o;
    float acc = 0.f;
    for (int cc = 0; cc < s; cc++) acc += base[(size_t)cc * 256];
    acc *= (1.0f / (float)s);
    const float ss = blk_reduce_sum(acc * acc, sb);
    const float sc = 1.0f / fmaxf(sqrtf(ss), 1e-12f);
    const float qv = acc * sc;
    qf[(size_t)r * 256 + o] = qv;
    qh[(size_t)r * 256 + o] = f2b(qv);
}

// bf16 MFMA GEMM + packed per-chunk top-2. grid (R/128, NC), 256 threads.
// 128x128 tile, 4 waves as 2x2 (wr,wc) of 64x64; BK=32.
// The two wc waves cover the SAME rows -> merged via LDS before the ptop write.
__global__ __launch_bounds__(256, 3) void k_amax1(
    const unsigned short* __restrict__ qh, const unsigned short* __restrict__ enh,
    uint2* __restrict__ ptop, int NC, int colsPerChunk) {
    __shared__ unsigned short As[4096];   // [row 0..127][k 0..31], 64B row stride
    __shared__ unsigned short Bs[4096];
    const int tid = threadIdx.x;
    const int lane = tid & 63;
    const int m = lane & 15, q4 = lane >> 4;
    const int w = tid >> 6;
    const int wr = w >> 1, wc = w & 1;
    const int rowbase = blockIdx.x * 128;
    const int chunk = blockIdx.y;
    const int srow = tid >> 2, sgr = tid & 3;

    const unsigned short* qa0 = qh + (size_t)(rowbase + srow) * 256 + sgr * 8;
    const unsigned short* qa1 = qa0 + 64 * 256;
    unsigned short* lA0 = &As[tid * 8];
    unsigned short* lA1 = &As[2048 + tid * 8];
    unsigned short* lB0 = &Bs[tid * 8];
    unsigned short* lB1 = &Bs[2048 + tid * 8];

    unsigned int t1[4][4], t2[4][4];
#pragma unroll
    for (int i = 0; i < 4; i++)
#pragma unroll
        for (int r = 0; r < 4; r++) { t1[i][r] = 0u; t2[i][r] = 0u; }

    const int ntiles = colsPerChunk >> 7;
    for (int nt = 0; nt < ntiles; nt++) {
        const int colchunk = chunk * colsPerChunk + nt * 128;
        const unsigned short* ba0 = enh + (size_t)(colchunk + srow) * 256 + sgr * 8;
        const unsigned short* ba1 = ba0 + 64 * 256;
        f32x4 acc[4][4];
#pragma unroll
        for (int i = 0; i < 4; i++)
#pragma unroll
            for (int j = 0; j < 4; j++) acc[i][j] = (f32x4){0.f, 0.f, 0.f, 0.f};

        for (int kb = 0; kb < 256; kb += 32) {
            __syncthreads();
            gl_lds16(qa0 + kb, lA0);
            gl_lds16(qa1 + kb, lA1);
            gl_lds16(ba0 + kb, lB0);
            gl_lds16(ba1 + kb, lB1);
            __syncthreads();
            bf16x8 af[4], bfr[4];
#pragma unroll
            for (int i = 0; i < 4; i++)
                af[i] = *(const bf16x8*)&As[(wr * 64 + i * 16 + m) * 32 + q4 * 8];
#pragma unroll
            for (int j = 0; j < 4; j++)
                bfr[j] = *(const bf16x8*)&Bs[(wc * 64 + j * 16 + m) * 32 + q4 * 8];
#pragma unroll
            for (int i = 0; i < 4; i++)
#pragma unroll
                for (int j = 0; j < 4; j++)
                    acc[i][j] = __builtin_amdgcn_mfma_f32_16x16x32_bf16(af[i], bfr[j], acc[i][j], 0, 0, 0);
        }
        // packed top-2 update: pack = bits(v+1.25) & ~0x1FFF | (8191-col)
#pragma unroll
        for (int j = 0; j < 4; j++) {
            const unsigned int ct = 8191u - (unsigned int)(colchunk + wc * 64 + j * 16 + m);
#pragma unroll
            for (int i = 0; i < 4; i++)
#pragma unroll
                for (int r = 0; r < 4; r++) {
                    const float wv = acc[i][j][r] + 1.25f;
                    const unsigned int cand = (__float_as_uint(wv) & 0xFFFFE000u) | ct;
                    const unsigned int nb1 = umaxu(t1[i][r], cand);
                    t2[i][r] = umaxu(t2[i][r], uminu(t1[i][r], cand));
                    t1[i][r] = nb1;
                }
        }
    }
    // butterfly top-2 merge across the 16 lanes of each quad
    unsigned int mb1[4][4], mb2[4][4];
#pragma unroll
    for (int i = 0; i < 4; i++)
#pragma unroll
        for (int r = 0; r < 4; r++) {
            unsigned int b1 = t1[i][r], b2 = t2[i][r];
#pragma unroll
            for (int d = 1; d < 16; d <<= 1) {
                const unsigned int o1 = (unsigned int)__shfl_xor((int)b1, d, 64);
                const unsigned int o2 = (unsigned int)__shfl_xor((int)b2, d, 64);
                const unsigned int mn = uminu(b1, o1);
                b1 = umaxu(b1, o1);
                b2 = umaxu(mn, umaxu(b2, o2));
            }
            mb1[i][r] = b1; mb2[i][r] = b2;
        }
    // cross-wave merge: wc=1 deposits to LDS, wc=0 merges + writes
    __syncthreads();                       // all As reads done before reuse
    uint2* msh = (uint2*)As;               // 128 rows x uint2 (1 KB)
    if (wc == 1 && m == 0) {
#pragma unroll
        for (int i = 0; i < 4; i++)
#pragma unroll
            for (int r = 0; r < 4; r++)
                msh[wr * 64 + i * 16 + q4 * 4 + r] = make_uint2(mb1[i][r], mb2[i][r]);
    }
    __syncthreads();
    if (wc == 0 && m == 0) {
#pragma unroll
        for (int i = 0; i < 4; i++)
#pragma unroll
            for (int r = 0; r < 4; r++) {
                const int rl = wr * 64 + i * 16 + q4 * 4 + r;
                const uint2 o = msh[rl];
                unsigned int b1 = mb1[i][r], b2 = mb2[i][r];
                const unsigned int mn = uminu(b1, o.x);
                b1 = umaxu(b1, o.x);
                b2 = umaxu(mn, umaxu(b2, o.y));
                ptop[(size_t)(rowbase + rl) * NC + chunk] = make_uint2(b1, b2);
            }
    }
}

// One block per row. Wave0 merges chunk top-2s; ambiguous rows fp64-rescore
// all 2NC candidates with 4 waves in parallel (4 elems/lane, shuffle reduce).
__global__ __launch_bounds__(256) void k_amax2(
    const uint2* __restrict__ ptop, const float* __restrict__ qf,
    const float* __restrict__ en, int* __restrict__ idxout,
    float* __restrict__ counts, int R, int NC) {
    __shared__ uint2 stop;
    __shared__ double swv[4];
    __shared__ int swi[4];
    const int r = blockIdx.x;
    const int tid = threadIdx.x, lane = tid & 63, w = tid >> 6;
    const uint2* pp = ptop + (size_t)r * NC;
    if (w == 0) {
        const uint2 p = (lane < NC) ? pp[lane] : make_uint2(0u, 0u);
        unsigned int b1 = p.x, b2 = p.y;
#pragma unroll
        for (int d = 1; d < 64; d <<= 1) {
            const unsigned int o1 = (unsigned int)__shfl_xor((int)b1, d, 64);
            const unsigned int o2 = (unsigned int)__shfl_xor((int)b2, d, 64);
            const unsigned int mn = uminu(b1, o1);
            b1 = umaxu(b1, o1);
            b2 = umaxu(mn, umaxu(b2, o2));
        }
        if (lane == 0) stop = make_uint2(b1, b2);
    }
    __syncthreads();
    const unsigned int b1 = stop.x, b2 = stop.y;
    const float* qp = qf + (size_t)r * 256;
    const float4 aq = *(const float4*)(qp + lane * 4);
    const bool ambig = (b1 & 0xFFFFE000u) - (b2 & 0xFFFFE000u) < 32768u;
    if (ambig) {
        double bv = -1e300; int bi = 0x7fffffff;
        const int ncand = 2 * NC;
        for (int ci = w; ci < ncand; ci += 4) {
            const uint2 p = pp[ci >> 1];
            const int col = 8191 - (int)(((ci & 1) ? p.y : p.x) & 0x1FFFu);
            const float4 be = *(const float4*)(en + (size_t)col * 256 + lane * 4);
            double s = (double)aq.x * be.x + (double)aq.y * be.y +
                       (double)aq.z * be.z + (double)aq.w * be.w;
#pragma unroll
            for (int d = 1; d < 64; d <<= 1) s += __shfl_xor(s, d, 64);
            if (s > bv || (s == bv && col < bi)) { bv = s; bi = col; }
        }
        if (lane == 0) { swv[w] = bv; swi[w] = bi; }
        __syncthreads();
        if (tid == 0) {
            double bvv = swv[0]; int bii = swi[0];
            for (int i = 1; i < 4; i++)
                if (swv[i] > bvv || (swv[i] == bvv && swi[i] < bii)) { bvv = swv[i]; bii = swi[i]; }
            idxout[r] = bii;
            atomicAdd(&counts[bii], 1.0f);
        }
    } else if (w == 0) {
        const int c1 = 8191 - (int)(b1 & 0x1FFFu);
        const int c2 = 8191 - (int)(b2 & 0x1FFFu);
        const float4 e1 = *(const float4*)(en + (size_t)c1 * 256 + lane * 4);
        const float4 e2v = *(const float4*)(en + (size_t)c2 * 256 + lane * 4);
        double s1 = (double)aq.x * e1.x + (double)aq.y * e1.y +
                    (double)aq.z * e1.z + (double)aq.w * e1.w;
        double s2 = (double)aq.x * e2v.x + (double)aq.y * e2v.y +
                    (double)aq.z * e2v.z + (double)aq.w * e2v.w;
#pragma unroll
        for (int d = 1; d < 64; d <<= 1) { s1 += __shfl_xor(s1, d, 64); s2 += __shfl_xor(s2, d, 64); }
        if (lane == 0) {
            const int best = (s2 > s1 || (s2 == s1 && c2 < c1)) ? c2 : c1;
            idxout[r] = best;
            atomicAdd(&counts[best], 1.0f);
        }
    }
}

// frest -= 0.5*u + 0.5*(conv(h)+bias); fused loss; optional q-emit (s=1) / z_q-emit
__global__ void k_epilogue(float* __restrict__ frest, const float* __restrict__ en,
    const float* __restrict__ esum, const float* __restrict__ e0, const float* __restrict__ e2,
    const float* __restrict__ bias, const int* __restrict__ idx,
    int g, int slog, int smask, double* __restrict__ lossp,
    int emitQ, float* __restrict__ qf, unsigned short* __restrict__ qh,
    int emitOut, const float* __restrict__ z, const float* __restrict__ rnorm,
    const int* __restrict__ inv, float* __restrict__ out) {
    __shared__ float sb[4];
    const int row = blockIdx.x;
    const int l = row >> 6, ch = row & 63;
    const int j = ch >> slog;
    const int r = l * g + j;
    const int i0 = idx[r];
    const int o = threadIdx.x;
    const size_t b0 = (size_t)i0 * 256 + o;
    float v = 0.5f * en[b0] + 0.5f * (esum[b0] + bias[o]);
    const int chs = ch & smask;
    if (chs == 0) {
        float t = -e0[b0];
        if (j > 0) t += e0[(size_t)idx[r - 1] * 256 + o];
        v += 0.5f * t;
    }
    if (chs == smask) {
        float t = -e2[b0];
        if (j < g - 1) t += e2[(size_t)idx[r + 1] * 256 + o];
        v += 0.5f * t;
    }
    const float nv = frest[(size_t)row * 256 + o] - v;
    const float ss = blk_reduce_sum(nv * nv, sb);
    if (o == 0) atomicAdd(&lossp[blockIdx.x & 255], (double)ss);
    if (emitOut) {
        const int b = l >> 4, t_ = l & 15;
        const int c = inv[(b << 6) + ch];
        const size_t zr = (size_t)((b << 10) + (t_ << 6) + c);
        out[zr * 256 + o] = z[zr * 256 + o] * rnorm[zr] - nv;   // z_q = z_LND - f_rest
    } else {
        frest[(size_t)row * 256 + o] = nv;
        if (emitQ) {   // s=1 stage: q row == normalized frest row
            const float sc = 1.0f / fmaxf(sqrtf(ss), 1e-12f);
            const float qv = nv * sc;
            qf[(size_t)row * 256 + o] = qv;
            qh[(size_t)row * 256 + o] = f2b(qv);
        }
    }
}

__global__ void k_losssum(const double* __restrict__ lossp, float* __restrict__ out) {
    __shared__ double sb[4];
    double s = 0.0;
    for (int i = threadIdx.x; i < 1024; i += 256) s += lossp[i];
#pragma unroll
    for (int off = 32; off; off >>= 1) s += __shfl_down(s, off, 64);
    if ((threadIdx.x & 63) == 0) sb[threadIdx.x >> 6] = s;
    __syncthreads();
    if (threadIdx.x == 0)
        out[OUT_LOSS] = (float)((sb[0] + sb[1] + sb[2] + sb[3]) * (1.25 / 4.0) / 16777216.0);
}

// idx_all (as float) and cluster_size_new
__global__ void k_final(const int* __restrict__ idxi, const float* __restrict__ counts,
                        const float* __restrict__ csin, float* __restrict__ out) {
    const int i = blockIdx.x * 256 + threadIdx.x;
    if (i < 87040) {
        const int l = i / 85, t = i - l * 85;
        int v;
        if (t == 0)       v = idxi[l];
        else if (t < 5)   v = idxi[1024 + l * 4 + (t - 1)];
        else if (t < 21)  v = idxi[5120 + l * 16 + (t - 5)];
        else              v = idxi[21504 + l * 64 + (t - 21)];
        out[OUT_IDX + i] = (float)v;
    } else if (i < 87040 + 8192) {
        const int v = i - 87040;
        out[OUT_CS + v] = 0.99f * csin[v] + 0.01f * counts[v];
    }
}

extern "C" void kernel_launch(void* const* d_in, const int* in_sizes, int n_in,
                              void* d_out, int out_size, void* d_ws, size_t ws_size,
                              hipStream_t stream) {
    (void)in_sizes; (void)n_in; (void)out_size; (void)ws_size;
    const float* z      = (const float*)d_in[0];
    const int*   ichans = (const int*)d_in[1];
    const float* emb    = (const float*)d_in[3];
    const float* phiw   = (const float*)d_in[4];
    const float* phib   = (const float*)d_in[5];
    const float* csin   = (const float*)d_in[6];
    float* ws  = (float*)d_ws;
    float* out = (float*)d_out;

    float* en    = ws + EN_OFF;
    unsigned short* enh = (unsigned short*)(ws + ENH_OFF);
    float* esum  = ws + ESUM_OFF;
    float* e0    = ws + E0_OFF;
    float* e2    = ws + E2_OFF;
    float* wsum  = ws + WSUM_OFF;
    float* w0    = ws + W0_OFF;
    float* w2    = ws + W2_OFF;
    float* frest = ws + FREST_OFF;
    float* qf    = ws + QF_OFF;
    unsigned short* qh = (unsigned short*)(ws + QH_OFF);
    uint2* ptop  = (uint2*)(ws + PTOP_OFF);
    int*   idxi  = (int*)(ws + IDXI_OFF);
    float* counts = ws + CNT_OFF;
    double* lossp = (double*)(ws + LOSSP_OFF);
    float* rnorm = ws + RNORM_OFF;
    int*   inv   = (int*)(ws + INV_OFF);

    // zero counts (8192 f32) + lossp (1024 doubles), contiguous
    hipMemsetAsync(counts, 0, 8192 * sizeof(float) + 1024 * sizeof(double), stream);

    k_norm_embed<<<V_DIM, 256, 0, stream>>>(emb, en, enh);
    k_prep_w<<<256, 256, 0, stream>>>(phiw, wsum, w0, w2);
    k_phi_gemm<<<dim3(V_DIM / 128, 2, 3), 256, 0, stream>>>(en, wsum, w0, w2, esum, e0, e2);
    k_invperm<<<64, 64, 0, stream>>>(ichans, inv);
    k_scatter<<<NROW, 256, 0, stream>>>(z, ichans, frest, rnorm);

    const int gs[4]    = {1, 4, 16, 64};
    const int ncs[4]   = {64, 32, 16, 8};
    const int cpcs[4]  = {128, 256, 512, 1024};
    const int offs[4]  = {0, 1024, 5120, 21504};
    const int slogs[4] = {6, 4, 2, 0};
    for (int st = 0; st < 4; st++) {
        const int g = gs[st], s = 64 / g, NC = ncs[st], R = L_DIM * g;
        if (st < 3)
            k_groupq<<<R, 256, 0, stream>>>(frest, qf, qh, g, s);
        k_amax1<<<dim3(R / 128, NC), 256, 0, stream>>>(qh, enh, ptop, NC, cpcs[st]);
        k_amax2<<<R, 256, 0, stream>>>(ptop, qf, en, idxi + offs[st], counts, R, NC);
        k_epilogue<<<NROW, 256, 0, stream>>>(frest, en, esum, e0, e2, phib, idxi + offs[st],
                                             g, slogs[st], s - 1, lossp + st * 256,
                                             (st == 2) ? 1 : 0, qf, qh,
                                             (st == 3) ? 1 : 0, z, rnorm, inv, out);
    }

    k_losssum<<<1, 256, 0, stream>>>(lossp, out);
    k_final<<<372, 256, 0, stream>>>(idxi, counts, csin, out);
}

// Round 5
// 1184.209 us; speedup vs baseline: 5.8081x; 1.1473x over previous
//
#include <hip/hip_runtime.h>

// Problem constants
#define D_DIM 256
#define V_DIM 8192
#define L_DIM 1024          // B*T
#define NROW 65536          // L*64 rows of f_rest
#define NELEM 16777216      // NROW * D

// Output layout (all float32 in d_out)
#define OUT_LOSS 16777216
#define OUT_IDX  16777217
#define OUT_CS   16864257

// Workspace float offsets
#define EN_OFF    ((size_t)0)
#define ENH_OFF   ((size_t)2097152)
#define ESUM_OFF  ((size_t)3145728)
#define E0_OFF    ((size_t)5242880)
#define E2_OFF    ((size_t)7340032)
#define WSUM_OFF  ((size_t)9437184)
#define W0_OFF    ((size_t)9502720)
#define W2_OFF    ((size_t)9568256)
#define FREST_OFF ((size_t)9633792)
#define QF_OFF    ((size_t)26411008)
#define QH_OFF    ((size_t)43188224)
#define PTOP_OFF  ((size_t)51576832)
#define IDXI_OFF  ((size_t)52625408)
#define CNT_OFF   ((size_t)52712448)
#define LOSSP_OFF ((size_t)52720640)
#define RNORM_OFF ((size_t)52722688)
#define INV_OFF   ((size_t)52788224)

typedef __attribute__((ext_vector_type(8))) short bf16x8;
typedef __attribute__((ext_vector_type(4))) float f32x4;

__device__ __forceinline__ unsigned int umaxu(unsigned int a, unsigned int b) { return a > b ? a : b; }
__device__ __forceinline__ unsigned int uminu(unsigned int a, unsigned int b) { return a < b ? a : b; }

__device__ __forceinline__ unsigned short f2b(float x) {
    unsigned int u = __float_as_uint(x);
    unsigned int r = (u + 0x7FFFu + ((u >> 16) & 1u)) >> 16;   // RNE
    return (unsigned short)r;
}

__device__ __forceinline__ void gl_lds16(const void* g, void* l) {
    __builtin_amdgcn_global_load_lds(
        (const __attribute__((address_space(1))) unsigned int*)g,
        (__attribute__((address_space(3))) unsigned int*)l, 16, 0, 0);
}

__device__ __forceinline__ float blk_reduce_sum(float v, float* sb) {
#pragma unroll
    for (int off = 32; off; off >>= 1) v += __shfl_down(v, off, 64);
    const int w = threadIdx.x >> 6;
    if ((threadIdx.x & 63) == 0) sb[w] = v;
    __syncthreads();
    return sb[0] + sb[1] + sb[2] + sb[3];
}

// Normalize embedding rows: en = emb / max(||emb||,1e-12), also emit bf16 copy
__global__ void k_norm_embed(const float* __restrict__ emb, float* __restrict__ en,
                             unsigned short* __restrict__ enh) {
    __shared__ float sb[4];
    const int v = blockIdx.x, o = threadIdx.x;
    const float x = emb[(size_t)v * 256 + o];
    const float ss = blk_reduce_sum(x * x, sb);
    const float sc = 1.0f / fmaxf(sqrtf(ss), 1e-12f);
    const float y = x * sc;
    en[(size_t)v * 256 + o] = y;
    enh[(size_t)v * 256 + o] = f2b(y);
}

// Repack phi_w (D,D,3) into Wsum / W0 / W2, each (o,i) row-major
__global__ void k_prep_w(const float* __restrict__ pw, float* __restrict__ wsum,
                         float* __restrict__ w0, float* __restrict__ w2) {
    const int i = blockIdx.x * 256 + threadIdx.x;
    const float a = pw[(size_t)i * 3 + 0];
    const float b = pw[(size_t)i * 3 + 1];
    const float c = pw[(size_t)i * 3 + 2];
    wsum[i] = a + b + c; w0[i] = a; w2[i] = c;
}

// E_k = e_n @ Wk^T (fp32 — feeds values, keep precision). grid (64, 2, 3)
__global__ __launch_bounds__(256) void k_phi_gemm(
    const float* __restrict__ en, const float* __restrict__ wsum,
    const float* __restrict__ w0, const float* __restrict__ w2,
    float* __restrict__ esum, float* __restrict__ e0, float* __restrict__ e2) {
    __shared__ __align__(16) float smem[4096];
    float (*As)[128] = (float (*)[128])smem;
    float (*Bs)[128] = (float (*)[128])(smem + 2048);
    const float* Bm; float* Cm;
    if (blockIdx.z == 0)      { Bm = wsum; Cm = esum; }
    else if (blockIdx.z == 1) { Bm = w0;   Cm = e0;   }
    else                      { Bm = w2;   Cm = e2;   }
    const int tid = threadIdx.x, tx = tid & 15, ty = tid >> 4;
    const int rowbase = blockIdx.x * 128, colbase = blockIdx.y * 128;
    float acc[8][8];
#pragma unroll
    for (int r = 0; r < 8; r++)
#pragma unroll
        for (int c = 0; c < 8; c++) acc[r][c] = 0.f;
    for (int kb = 0; kb < 256; kb += 16) {
        __syncthreads();
        {
            const int lr = tid >> 1, k0 = (tid & 1) << 3;
            const float4* ap = (const float4*)(en + ((size_t)(rowbase + lr)) * 256 + kb + k0);
            const float4 a0 = ap[0], a1 = ap[1];
            const float4* bp = (const float4*)(Bm + ((size_t)(colbase + lr)) * 256 + kb + k0);
            const float4 b0 = bp[0], b1 = bp[1];
            As[k0+0][lr]=a0.x; As[k0+1][lr]=a0.y; As[k0+2][lr]=a0.z; As[k0+3][lr]=a0.w;
            As[k0+4][lr]=a1.x; As[k0+5][lr]=a1.y; As[k0+6][lr]=a1.z; As[k0+7][lr]=a1.w;
            Bs[k0+0][lr]=b0.x; Bs[k0+1][lr]=b0.y; Bs[k0+2][lr]=b0.z; Bs[k0+3][lr]=b0.w;
            Bs[k0+4][lr]=b1.x; Bs[k0+5][lr]=b1.y; Bs[k0+6][lr]=b1.z; Bs[k0+7][lr]=b1.w;
        }
        __syncthreads();
#pragma unroll
        for (int k = 0; k < 16; k++) {
            const float4 av0 = *(const float4*)&As[k][ty << 3];
            const float4 av1 = *(const float4*)&As[k][(ty << 3) + 4];
            const float4 bv0 = *(const float4*)&Bs[k][tx << 3];
            const float4 bv1 = *(const float4*)&Bs[k][(tx << 3) + 4];
            const float a[8] = {av0.x, av0.y, av0.z, av0.w, av1.x, av1.y, av1.z, av1.w};
            const float b[8] = {bv0.x, bv0.y, bv0.z, bv0.w, bv1.x, bv1.y, bv1.z, bv1.w};
#pragma unroll
            for (int r = 0; r < 8; r++)
#pragma unroll
                for (int c = 0; c < 8; c++) acc[r][c] = fmaf(a[r], b[c], acc[r][c]);
        }
    }
#pragma unroll
    for (int r = 0; r < 8; r++) {
        float4 o0 = {acc[r][0], acc[r][1], acc[r][2], acc[r][3]};
        float4 o1 = {acc[r][4], acc[r][5], acc[r][6], acc[r][7]};
        float* cp = Cm + ((size_t)(rowbase + (ty << 3) + r)) * 256 + colbase + (tx << 3);
        *(float4*)cp = o0; *(float4*)(cp + 4) = o1;
    }
}

// inverse channel permutation: inv[b][ch] = c
__global__ void k_invperm(const int* __restrict__ ichans, int* __restrict__ inv) {
    const int b = blockIdx.x, c = threadIdx.x;
    inv[(b << 6) + ichans[(b << 10) + c]] = c;
}

// Normalize z rows, scatter into permuted layout (frest), save 1/||z|| per row
__global__ void k_scatter(const float* __restrict__ z, const int* __restrict__ ichans,
                          float* __restrict__ frest, float* __restrict__ rnorm) {
    __shared__ float sb[4];
    const int zrow = blockIdx.x;
    const int b = zrow >> 10, n = zrow & 1023;
    const int t = n >> 6, c = n & 63;
    const int o = threadIdx.x;
    const float x = z[(size_t)zrow * 256 + o];
    const float ss = blk_reduce_sum(x * x, sb);
    const float sc = 1.0f / fmaxf(sqrtf(ss), 1e-12f);
    const int ch = ichans[(b << 10) + c];
    frest[((size_t)(((b << 4) + t) * 64 + ch)) * 256 + o] = x * sc;
    if (o == 0) rnorm[zrow] = sc;
}

// q[r] = l2norm(mean over s channels of frest) — used for stage 0 only
__global__ void k_groupq(const float* __restrict__ frest, float* __restrict__ qf,
                         unsigned short* __restrict__ qh, int g, int s) {
    __shared__ float sb[4];
    const int r = blockIdx.x;
    const int l = r / g, j = r - l * g;
    const int o = threadIdx.x;
    const float* base = frest + ((size_t)l * 64 + (size_t)j * s) * 256 + o;
    float acc = 0.f;
    for (int cc = 0; cc < s; cc++) acc += base[(size_t)cc * 256];
    acc *= (1.0f / (float)s);
    const float ss = blk_reduce_sum(acc * acc, sb);
    const float sc = 1.0f / fmaxf(sqrtf(ss), 1e-12f);
    const float qv = acc * sc;
    qf[(size_t)r * 256 + o] = qv;
    qh[(size_t)r * 256 + o] = f2b(qv);
}

// bf16 MFMA GEMM + packed per-chunk top-2. grid (R/128, NC), 256 threads.
// 128x128 tile, 4 waves as 2x2 (wr,wc) of 64x64; BK=32, double-buffered LDS,
// ONE barrier per BK step (stage step+1 into buf^1 while computing buf).
// Accumulators init to +1.25 so packed uint compare needs no bias add.
__global__ __launch_bounds__(256, 3) void k_amax1(
    const unsigned short* __restrict__ qh, const unsigned short* __restrict__ enh,
    uint2* __restrict__ ptop, int NC, int colsPerChunk) {
    __shared__ unsigned short As[2][4096];   // [buf][row 0..127][k 0..31]
    __shared__ unsigned short Bs[2][4096];
    const int tid = threadIdx.x;
    const int lane = tid & 63;
    const int m = lane & 15, q4 = lane >> 4;
    const int w = tid >> 6;
    const int wr = w >> 1, wc = w & 1;
    const int rowbase = blockIdx.x * 128;
    const int chunk = blockIdx.y;
    const int colbase0 = chunk * colsPerChunk;
    const int srow = tid >> 2, sgr = tid & 3;

    const unsigned short* qa0 = qh + (size_t)(rowbase + srow) * 256 + sgr * 8;
    const unsigned short* qa1 = qa0 + 64 * 256;
    const unsigned short* eb0 = enh + (size_t)srow * 256 + sgr * 8;
    const unsigned short* eb1 = eb0 + 64 * 256;
    const int loff = tid * 8;

    unsigned int t1[4][4], t2[4][4];
    f32x4 acc[4][4];
#pragma unroll
    for (int i = 0; i < 4; i++)
#pragma unroll
        for (int r = 0; r < 4; r++) {
            t1[i][r] = 0u; t2[i][r] = 0u;
            acc[i][r] = (f32x4){1.25f, 1.25f, 1.25f, 1.25f};
        }

    const int nsteps = (colsPerChunk >> 7) * 8;   // BK=32 steps over all col tiles
    // prefetch step 0 into buf 0
    {
        gl_lds16(qa0, &As[0][loff]);
        gl_lds16(qa1, &As[0][2048 + loff]);
        const size_t bgo = (size_t)colbase0 * 256;
        gl_lds16(eb0 + bgo, &Bs[0][loff]);
        gl_lds16(eb1 + bgo, &Bs[0][2048 + loff]);
    }
    for (int step = 0; step < nsteps; step++) {
        const int buf = step & 1;
        __syncthreads();    // staging of `step` landed; prior reads of buf done
        if (step + 1 < nsteps) {
            const int kb1 = (step + 1) & 7;
            const int tile1 = (step + 1) >> 3;
            gl_lds16(qa0 + kb1 * 32, &As[buf ^ 1][loff]);
            gl_lds16(qa1 + kb1 * 32, &As[buf ^ 1][2048 + loff]);
            const size_t bgo = (size_t)(colbase0 + tile1 * 128) * 256 + kb1 * 32;
            gl_lds16(eb0 + bgo, &Bs[buf ^ 1][loff]);
            gl_lds16(eb1 + bgo, &Bs[buf ^ 1][2048 + loff]);
        }
        bf16x8 af[4], bfr[4];
#pragma unroll
        for (int i = 0; i < 4; i++)
            af[i] = *(const bf16x8*)&As[buf][(wr * 64 + i * 16 + m) * 32 + q4 * 8];
#pragma unroll
        for (int j = 0; j < 4; j++)
            bfr[j] = *(const bf16x8*)&Bs[buf][(wc * 64 + j * 16 + m) * 32 + q4 * 8];
#pragma unroll
        for (int i = 0; i < 4; i++)
#pragma unroll
            for (int j = 0; j < 4; j++)
                acc[i][j] = __builtin_amdgcn_mfma_f32_16x16x32_bf16(af[i], bfr[j], acc[i][j], 0, 0, 0);
        if ((step & 7) == 7) {
            // end of 128-col tile: fold acc into packed top-2, reset acc
            const int colchunk = colbase0 + (step >> 3) * 128;
#pragma unroll
            for (int j = 0; j < 4; j++) {
                const unsigned int ct = 8191u - (unsigned int)(colchunk + wc * 64 + j * 16 + m);
#pragma unroll
                for (int i = 0; i < 4; i++)
#pragma unroll
                    for (int r = 0; r < 4; r++) {
                        const unsigned int cand =
                            (__float_as_uint(acc[i][j][r]) & 0xFFFFE000u) | (ct & 0x1FFFu);
                        const unsigned int nb1 = umaxu(t1[i][r], cand);
                        t2[i][r] = umaxu(t2[i][r], uminu(t1[i][r], cand));
                        t1[i][r] = nb1;
                        acc[i][j][r] = 1.25f;
                    }
            }
        }
    }
    // butterfly top-2 merge across the 16 lanes of each quad
    unsigned int mb1[4][4], mb2[4][4];
#pragma unroll
    for (int i = 0; i < 4; i++)
#pragma unroll
        for (int r = 0; r < 4; r++) {
            unsigned int b1 = t1[i][r], b2 = t2[i][r];
#pragma unroll
            for (int d = 1; d < 16; d <<= 1) {
                const unsigned int o1 = (unsigned int)__shfl_xor((int)b1, d, 64);
                const unsigned int o2 = (unsigned int)__shfl_xor((int)b2, d, 64);
                const unsigned int mn = uminu(b1, o1);
                b1 = umaxu(b1, o1);
                b2 = umaxu(mn, umaxu(b2, o2));
            }
            mb1[i][r] = b1; mb2[i][r] = b2;
        }
    // cross-wave merge: wc=1 deposits to LDS, wc=0 merges + writes
    __syncthreads();
    uint2* msh = (uint2*)&As[0][0];
    if (wc == 1 && m == 0) {
#pragma unroll
        for (int i = 0; i < 4; i++)
#pragma unroll
            for (int r = 0; r < 4; r++)
                msh[wr * 64 + i * 16 + q4 * 4 + r] = make_uint2(mb1[i][r], mb2[i][r]);
    }
    __syncthreads();
    if (wc == 0 && m == 0) {
#pragma unroll
        for (int i = 0; i < 4; i++)
#pragma unroll
            for (int r = 0; r < 4; r++) {
                const int rl = wr * 64 + i * 16 + q4 * 4 + r;
                const uint2 o = msh[rl];
                unsigned int b1 = mb1[i][r], b2 = mb2[i][r];
                const unsigned int mn = uminu(b1, o.x);
                b1 = umaxu(b1, o.x);
                b2 = umaxu(mn, umaxu(b2, o.y));
                ptop[(size_t)(rowbase + rl) * NC + chunk] = make_uint2(b1, b2);
            }
    }
}

// One block per row. Wave0 merges chunk top-2s; ambiguous rows fp64-rescore
// all 2NC candidates with 4 waves in parallel (4 elems/lane, shuffle reduce).
__global__ __launch_bounds__(256) void k_amax2(
    const uint2* __restrict__ ptop, const float* __restrict__ qf,
    const float* __restrict__ en, int* __restrict__ idxout,
    float* __restrict__ counts, int R, int NC) {
    __shared__ uint2 stop;
    __shared__ double swv[4];
    __shared__ int swi[4];
    const int r = blockIdx.x;
    const int tid = threadIdx.x, lane = tid & 63, w = tid >> 6;
    const uint2* pp = ptop + (size_t)r * NC;
    if (w == 0) {
        const uint2 p = (lane < NC) ? pp[lane] : make_uint2(0u, 0u);
        unsigned int b1 = p.x, b2 = p.y;
#pragma unroll
        for (int d = 1; d < 64; d <<= 1) {
            const unsigned int o1 = (unsigned int)__shfl_xor((int)b1, d, 64);
            const unsigned int o2 = (unsigned int)__shfl_xor((int)b2, d, 64);
            const unsigned int mn = uminu(b1, o1);
            b1 = umaxu(b1, o1);
            b2 = umaxu(mn, umaxu(b2, o2));
        }
        if (lane == 0) stop = make_uint2(b1, b2);
    }
    __syncthreads();
    const unsigned int b1 = stop.x, b2 = stop.y;
    const float* qp = qf + (size_t)r * 256;
    const float4 aq = *(const float4*)(qp + lane * 4);
    const bool ambig = (b1 & 0xFFFFE000u) - (b2 & 0xFFFFE000u) < 32768u;
    if (ambig) {
        double bv = -1e300; int bi = 0x7fffffff;
        const int ncand = 2 * NC;
        for (int ci = w; ci < ncand; ci += 4) {
            const uint2 p = pp[ci >> 1];
            const int col = 8191 - (int)(((ci & 1) ? p.y : p.x) & 0x1FFFu);
            const float4 be = *(const float4*)(en + (size_t)col * 256 + lane * 4);
            double s = (double)aq.x * be.x + (double)aq.y * be.y +
                       (double)aq.z * be.z + (double)aq.w * be.w;
#pragma unroll
            for (int d = 1; d < 64; d <<= 1) s += __shfl_xor(s, d, 64);
            if (s > bv || (s == bv && col < bi)) { bv = s; bi = col; }
        }
        if (lane == 0) { swv[w] = bv; swi[w] = bi; }
        __syncthreads();
        if (tid == 0) {
            double bvv = swv[0]; int bii = swi[0];
            for (int i = 1; i < 4; i++)
                if (swv[i] > bvv || (swv[i] == bvv && swi[i] < bii)) { bvv = swv[i]; bii = swi[i]; }
            idxout[r] = bii;
            atomicAdd(&counts[bii], 1.0f);
        }
    } else if (w == 0) {
        const int c1 = 8191 - (int)(b1 & 0x1FFFu);
        const int c2 = 8191 - (int)(b2 & 0x1FFFu);
        const float4 e1 = *(const float4*)(en + (size_t)c1 * 256 + lane * 4);
        const float4 e2v = *(const float4*)(en + (size_t)c2 * 256 + lane * 4);
        double s1 = (double)aq.x * e1.x + (double)aq.y * e1.y +
                    (double)aq.z * e1.z + (double)aq.w * e1.w;
        double s2 = (double)aq.x * e2v.x + (double)aq.y * e2v.y +
                    (double)aq.z * e2v.z + (double)aq.w * e2v.w;
#pragma unroll
        for (int d = 1; d < 64; d <<= 1) { s1 += __shfl_xor(s1, d, 64); s2 += __shfl_xor(s2, d, 64); }
        if (lane == 0) {
            const int best = (s2 > s1 || (s2 == s1 && c2 < c1)) ? c2 : c1;
            idxout[r] = best;
            atomicAdd(&counts[best], 1.0f);
        }
    }
}

// Fused epilogue: frest -= 0.5*u + 0.5*(conv(h)+bias); loss; next-stage q
// (mean over rpb rows + l2norm) or z_q emit. One block per next-stage group.
__global__ __launch_bounds__(256) void k_epi(
    float* __restrict__ frest, const float* __restrict__ en,
    const float* __restrict__ esum, const float* __restrict__ e0, const float* __restrict__ e2,
    const float* __restrict__ bias, const int* __restrict__ idx,
    int g, int slog, int smask, double* __restrict__ lossp, int rpb,
    int emitQ, float* __restrict__ qf, unsigned short* __restrict__ qh,
    int emitOut, const float* __restrict__ z, const float* __restrict__ rnorm,
    const int* __restrict__ inv, float* __restrict__ out) {
    __shared__ float sb[8];
    const int bid = blockIdx.x;
    const int o = threadIdx.x;
    const int row0 = bid * rpb;
    const int l = row0 >> 6;
    float qacc = 0.f, lsum = 0.f;
    for (int rr = 0; rr < rpb; rr++) {
        const int row = row0 + rr;
        const int ch = row & 63;
        const int j = ch >> slog;
        const int r = l * g + j;
        const int i0 = idx[r];
        const size_t b0 = (size_t)i0 * 256 + o;
        float v = 0.5f * en[b0] + 0.5f * (esum[b0] + bias[o]);
        const int chs = ch & smask;
        if (chs == 0) {
            float t = -e0[b0];
            if (j > 0) t += e0[(size_t)idx[r - 1] * 256 + o];
            v += 0.5f * t;
        }
        if (chs == smask) {
            float t = -e2[b0];
            if (j < g - 1) t += e2[(size_t)idx[r + 1] * 256 + o];
            v += 0.5f * t;
        }
        const float nv = frest[(size_t)row * 256 + o] - v;
        qacc += nv; lsum = fmaf(nv, nv, lsum);
        if (emitOut) {
            const int b = l >> 4, t_ = l & 15;
            const int c = inv[(b << 6) + ch];
            const size_t zr = (size_t)((b << 10) + (t_ << 6) + c);
            out[zr * 256 + o] = z[zr * 256 + o] * rnorm[zr] - nv;   // z_q
        } else {
            frest[(size_t)row * 256 + o] = nv;
        }
    }
    // dual block-reduce: loss and ||q||^2
    const float qm = qacc * (1.0f / (float)rpb);
    float a = lsum, bq = qm * qm;
#pragma unroll
    for (int off = 32; off; off >>= 1) {
        a += __shfl_down(a, off, 64);
        bq += __shfl_down(bq, off, 64);
    }
    const int w = o >> 6;
    if ((o & 63) == 0) { sb[w] = a; sb[4 + w] = bq; }
    __syncthreads();
    if (o == 0)
        atomicAdd(&lossp[bid & 255], (double)(sb[0] + sb[1] + sb[2] + sb[3]));
    if (emitQ) {
        const float qs = sb[4] + sb[5] + sb[6] + sb[7];
        const float sc = 1.0f / fmaxf(sqrtf(qs), 1e-12f);
        const float qv = qm * sc;
        qf[(size_t)bid * 256 + o] = qv;
        qh[(size_t)bid * 256 + o] = f2b(qv);
    }
}

__global__ void k_losssum(const double* __restrict__ lossp, float* __restrict__ out) {
    __shared__ double sb[4];
    double s = 0.0;
    for (int i = threadIdx.x; i < 1024; i += 256) s += lossp[i];
#pragma unroll
    for (int off = 32; off; off >>= 1) s += __shfl_down(s, off, 64);
    if ((threadIdx.x & 63) == 0) sb[threadIdx.x >> 6] = s;
    __syncthreads();
    if (threadIdx.x == 0)
        out[OUT_LOSS] = (float)((sb[0] + sb[1] + sb[2] + sb[3]) * (1.25 / 4.0) / 16777216.0);
}

// idx_all (as float) and cluster_size_new
__global__ void k_final(const int* __restrict__ idxi, const float* __restrict__ counts,
                        const float* __restrict__ csin, float* __restrict__ out) {
    const int i = blockIdx.x * 256 + threadIdx.x;
    if (i < 87040) {
        const int l = i / 85, t = i - l * 85;
        int v;
        if (t == 0)       v = idxi[l];
        else if (t < 5)   v = idxi[1024 + l * 4 + (t - 1)];
        else if (t < 21)  v = idxi[5120 + l * 16 + (t - 5)];
        else              v = idxi[21504 + l * 64 + (t - 21)];
        out[OUT_IDX + i] = (float)v;
    } else if (i < 87040 + 8192) {
        const int v = i - 87040;
        out[OUT_CS + v] = 0.99f * csin[v] + 0.01f * counts[v];
    }
}

extern "C" void kernel_launch(void* const* d_in, const int* in_sizes, int n_in,
                              void* d_out, int out_size, void* d_ws, size_t ws_size,
                              hipStream_t stream) {
    (void)in_sizes; (void)n_in; (void)out_size; (void)ws_size;
    const float* z      = (const float*)d_in[0];
    const int*   ichans = (const int*)d_in[1];
    const float* emb    = (const float*)d_in[3];
    const float* phiw   = (const float*)d_in[4];
    const float* phib   = (const float*)d_in[5];
    const float* csin   = (const float*)d_in[6];
    float* ws  = (float*)d_ws;
    float* out = (float*)d_out;

    float* en    = ws + EN_OFF;
    unsigned short* enh = (unsigned short*)(ws + ENH_OFF);
    float* esum  = ws + ESUM_OFF;
    float* e0    = ws + E0_OFF;
    float* e2    = ws + E2_OFF;
    float* wsum  = ws + WSUM_OFF;
    float* w0    = ws + W0_OFF;
    float* w2    = ws + W2_OFF;
    float* frest = ws + FREST_OFF;
    float* qf    = ws + QF_OFF;
    unsigned short* qh = (unsigned short*)(ws + QH_OFF);
    uint2* ptop  = (uint2*)(ws + PTOP_OFF);
    int*   idxi  = (int*)(ws + IDXI_OFF);
    float* counts = ws + CNT_OFF;
    double* lossp = (double*)(ws + LOSSP_OFF);
    float* rnorm = ws + RNORM_OFF;
    int*   inv   = (int*)(ws + INV_OFF);

    // zero counts (8192 f32) + lossp (1024 doubles), contiguous
    hipMemsetAsync(counts, 0, 8192 * sizeof(float) + 1024 * sizeof(double), stream);

    k_norm_embed<<<V_DIM, 256, 0, stream>>>(emb, en, enh);
    k_prep_w<<<256, 256, 0, stream>>>(phiw, wsum, w0, w2);
    k_phi_gemm<<<dim3(V_DIM / 128, 2, 3), 256, 0, stream>>>(en, wsum, w0, w2, esum, e0, e2);
    k_invperm<<<64, 64, 0, stream>>>(ichans, inv);
    k_scatter<<<NROW, 256, 0, stream>>>(z, ichans, frest, rnorm);
    k_groupq<<<L_DIM, 256, 0, stream>>>(frest, qf, qh, 1, 64);   // stage-0 q

    const int gs[4]    = {1, 4, 16, 64};
    const int ncs[4]   = {64, 32, 16, 8};
    const int cpcs[4]  = {128, 256, 512, 1024};
    const int offs[4]  = {0, 1024, 5120, 21504};
    const int slogs[4] = {6, 4, 2, 0};
    const int rpbs[4]  = {16, 4, 1, 1};      // rows per epilogue block = 64/g_next
    for (int st = 0; st < 4; st++) {
        const int g = gs[st], s = 64 / g, NC = ncs[st], R = L_DIM * g;
        k_amax1<<<dim3(R / 128, NC), 256, 0, stream>>>(qh, enh, ptop, NC, cpcs[st]);
        k_amax2<<<R, 256, 0, stream>>>(ptop, qf, en, idxi + offs[st], counts, R, NC);
        k_epi<<<NROW / rpbs[st], 256, 0, stream>>>(frest, en, esum, e0, e2, phib,
                                                   idxi + offs[st], g, slogs[st], s - 1,
                                                   lossp + st * 256, rpbs[st],
                                                   (st < 3) ? 1 : 0, qf, qh,
                                                   (st == 3) ? 1 : 0, z, rnorm, inv, out);
    }

    k_losssum<<<1, 256, 0, stream>>>(lossp, out);
    k_final<<<372, 256, 0, stream>>>(idxi, counts, csin, out);
}